// Round 7
// baseline (1192.066 us; speedup 1.0000x reference)
//
#include <hip/hip_runtime.h>

#define N_NODES 50000
#define N_EDGES 800000
#define PDIM 3
#define FDIM 64
#define MDIM 32
#define NLAYERS 2
#define EINDIM 129
#define H1 258          // 2*EIN
#define CH 128          // 4*M
#define NH 128          // 2*F
#define XDIM 67         // P+F
#define H1T 288         // padded h dim (18 tiles of 16)
#define HSTR 168        // hLds col stride (bf16): 336B = 21 quanta (odd -> conflict-free b128)
#define W1T_K 136       // w1t k-dim (128 + 8 pad)
#define MLSTR 40        // ml LDS row stride (bf16)

typedef __attribute__((ext_vector_type(8))) short short8;
typedef __attribute__((ext_vector_type(4))) float f32x4;

#define LOG2E 1.4426950408889634f

__device__ __forceinline__ float fsilu(float x) {
  float e = __builtin_amdgcn_exp2f(-x * LOG2E);
  return x * __builtin_amdgcn_rcpf(1.0f + e);
}

__device__ __forceinline__ float ftanh(float x) {
  float xc = fminf(fmaxf(x, -15.0f), 15.0f);
  float E = __builtin_amdgcn_exp2f(2.0f * LOG2E * xc);
  return (E - 1.0f) * __builtin_amdgcn_rcpf(E + 1.0f);
}

__device__ __forceinline__ unsigned short f2bf(float f) {
  union { float f; unsigned u; } v; v.f = f;
  unsigned r = v.u + 0x7FFF + ((v.u >> 16) & 1);  // RNE
  return (unsigned short)(r >> 16);
}

__device__ __forceinline__ float bf2f(unsigned short u) {
  union { unsigned u; float f; } v; v.u = ((unsigned)u) << 16;
  return v.f;
}

__device__ __forceinline__ unsigned cvt_pk(float lo, float hi) {
  unsigned r;
  asm("v_cvt_pk_bf16_f32 %0, %1, %2" : "=v"(r) : "v"(lo), "v"(hi));
  return r;
}

// bijective XCD-chunk swizzle (m204): consecutive swizzled ids stay on one XCD
__device__ __forceinline__ int xcd_swz(int bid, int nwg) {
  const int nx = 8;
  int q = nwg / nx, r = nwg % nx;
  int xcd = bid % nx, idx = bid / nx;
  return (xcd < r) ? xcd * (q + 1) + idx : r * (q + 1) + (xcd - r) * q + idx;
}

// ---- CSR build ----
__global__ void count_kernel(const int* __restrict__ ei, int* __restrict__ cnt) {
  int e = blockIdx.x * 256 + threadIdx.x;
  if (e < N_EDGES) atomicAdd(&cnt[ei[N_EDGES + e]], 1);
}

__global__ __launch_bounds__(1024)
void scan_kernel(const int* __restrict__ cnt, int* __restrict__ csr, int* __restrict__ cursor) {
  __shared__ int partial[1024];
  const int tid = threadIdx.x;
  const int CHUNK = 49;
  int base = tid * CHUNK;
  int s = 0;
  for (int i = 0; i < CHUNK; ++i) {
    int idx = base + i;
    if (idx < N_NODES) s += cnt[idx];
  }
  partial[tid] = s;
  __syncthreads();
  for (int off = 1; off < 1024; off <<= 1) {
    int v = (tid >= off) ? partial[tid - off] : 0;
    __syncthreads();
    partial[tid] += v;
    __syncthreads();
  }
  int run = partial[tid] - s;
  for (int i = 0; i < CHUNK; ++i) {
    int idx = base + i;
    if (idx < N_NODES) {
      csr[idx] = run;
      cursor[idx] = run;
      run += cnt[idx];
    }
  }
  if (tid == 1023) csr[N_NODES] = run;
}

// sort edges by dst: slot p gets (src, dst)
__global__ void rank_kernel(const int* __restrict__ ei, int* __restrict__ cursor,
                            int* __restrict__ srcS, int* __restrict__ dstS) {
  int e = blockIdx.x * 256 + threadIdx.x;
  if (e < N_EDGES) {
    int s = ei[e];
    int d = ei[N_EDGES + e];
    int p = atomicAdd(&cursor[d], 1);
    srcS[p] = s;
    dstS[p] = d;
  }
}

// ---- weight prep ----
__global__ void prep_weights(const float* __restrict__ eW1, const float* __restrict__ eW2,
                             const float* __restrict__ cW1, const float* __restrict__ eb1,
                             unsigned short* __restrict__ w1t, unsigned short* __restrict__ w2t,
                             unsigned short* __restrict__ cw1t,
                             float* __restrict__ b1p, float* __restrict__ wrp) {
  int idx = blockIdx.x * 256 + threadIdx.x;
  const int n1 = NLAYERS * H1T * W1T_K;
  const int n2 = NLAYERS * MDIM * H1T;
  const int n3 = NLAYERS * CH * MDIM;
  const int n4 = NLAYERS * H1T;
  if (idx < n1) {
    int k = idx % W1T_K;
    int rest = idx / W1T_K;
    int j = rest % H1T;
    int l = rest / H1T;
    float v = (k < 128 && j < H1) ? eW1[(l * EINDIM + k) * H1 + j] : 0.0f;
    w1t[idx] = f2bf(v);
  } else if (idx < n1 + n2) {
    int t = idx - n1;
    int k = t % H1T;
    int rest = t / H1T;
    int n = rest % MDIM;
    int l = rest / MDIM;
    float v = (k < H1) ? eW2[(l * H1 + k) * MDIM + n] : 0.0f;
    w2t[t] = f2bf(v);
  } else if (idx < n1 + n2 + n3) {
    int t = idx - n1 - n2;
    int k = t % MDIM;
    int rest = t / MDIM;
    int n = rest % CH;
    int l = rest / CH;
    cw1t[t] = f2bf(cW1[(l * MDIM + k) * CH + n]);
  } else if (idx < n1 + n2 + n3 + n4) {
    int t = idx - n1 - n2 - n3;
    int j = t % H1T;
    int l = t / H1T;
    b1p[t] = (j < H1) ? eb1[l * H1 + j] : 0.0f;
  } else if (idx < n1 + n2 + n3 + 2 * n4) {
    int t = idx - n1 - n2 - n3 - n4;
    int j = t % H1T;
    int l = t / H1T;
    wrp[t] = (j < H1) ? eW1[((size_t)l * EINDIM + 128) * H1 + j] : 0.0f;
  }
}

// convert X features to bf16 [N][64]
__global__ void convert_x(const float* __restrict__ X, unsigned short* __restrict__ Xb) {
  int idx = blockIdx.x * 256 + threadIdx.x;
  if (idx >= N_NODES * 8) return;
  int n = idx >> 3, c = idx & 7;
  const float* src = X + n * XDIM + PDIM + c * 8;
  short8 v;
  #pragma unroll
  for (int i = 0; i < 8; ++i) v[i] = (short)f2bf(src[i]);
  *(short8*)&Xb[n * 64 + c * 8] = v;
}

// Wave-owned edge kernel: wave wid owns edges [e0+wid*16, e0+wid*16+16).
// No __syncthreads in the body — all LDS traffic is same-wave (wave-synchronous).
__global__ __launch_bounds__(256, 6)
void edge_mfma_kernel(const float* __restrict__ X,
                      const unsigned short* __restrict__ Xb,
                      const int* __restrict__ srcS, const int* __restrict__ dstS,
                      const unsigned short* __restrict__ w1t,
                      const float* __restrict__ b1p, const float* __restrict__ wrp,
                      const unsigned short* __restrict__ w2t, const float* __restrict__ eb2,
                      const unsigned short* __restrict__ cw1t, const float* __restrict__ cb1,
                      const float* __restrict__ cW2, const float* __restrict__ cb2,
                      const float* __restrict__ cscale,
                      unsigned short* __restrict__ ms, float* __restrict__ mh4,
                      int layer)
{
  __shared__ unsigned short hLds[64 * HSTR];   // 21504 B, row = edge, col = local j (half)
  __shared__ unsigned short ml[64 * MLSTR];    //  5120 B, row = edge, col = n

  const int tid = threadIdx.x;
  const int lane = tid & 63;
  const int wid = tid >> 6;
  const int ln15 = lane & 15;
  const int kg = lane >> 4;
  const int e0 = xcd_swz(blockIdx.x, gridDim.x) * 64;
  const int emine = e0 + wid * 16 + ln15;   // this lane's edge (all kg duplicate)
  const int erow = wid * 16 + ln15;

  // per-lane edge data (lanes 16-63 duplicate lanes 0-15: broadcast loads)
  const int ns = srcS[emine];
  const int nd = dstS[emine];
  float rx = X[ns * XDIM + 0] - X[nd * XDIM + 0];
  float ry = X[ns * XDIM + 1] - X[nd * XDIM + 1];
  float rz = X[ns * XDIM + 2] - X[nd * XDIM + 2];
  const float distv = rx * rx + ry * ry + rz * rz;

  // B-fragments of e_inT for my edge: lane ln15 = col = edge, kg*8+i = k
  short8 einB[4];
  #pragma unroll
  for (int ks = 0; ks < 4; ++ks) {
    int node = (ks < 2) ? nd : ns;
    einB[ks] = *(const short8*)&Xb[node * 64 + (ks & 1) * 32 + kg * 8];
  }

  const unsigned short* W1T = w1t + layer * H1T * W1T_K;
  const float* B1P = b1p + layer * H1T;
  const float* WRP = wrp + layer * H1T;
  const unsigned short* W2T = w2t + layer * MDIM * H1T;
  const float* B2 = eb2 + layer * MDIM;

  float b20 = B2[ln15], b21 = B2[16 + ln15];
  f32x4 mac0 = {b20, b20, b20, b20};
  f32x4 mac1 = {b21, b21, b21, b21};

  // ---- phases B+C in two k-halves (10 + 8 j-tiles), hLds reused ----
  #pragma unroll 1
  for (int half = 0; half < 2; ++half) {
    const int jt0 = half ? 10 : 0;
    const int njt = half ? 8 : 10;
    // phase B: h rows for my 16 edges, cols [jt0*16, jt0*16+njt*16)
    #pragma unroll 1
    for (int j = 0; j < njt; ++j) {
      const int jt = jt0 + j;
      f32x4 b4 = *(const f32x4*)&B1P[jt * 16 + kg * 4];
      f32x4 w4 = *(const f32x4*)&WRP[jt * 16 + kg * 4];
      short8 a[4];
      #pragma unroll
      for (int ks = 0; ks < 4; ++ks)
        a[ks] = *(const short8*)&W1T[(jt * 16 + ln15) * W1T_K + ks * 32 + kg * 8];
      f32x4 acc;
      #pragma unroll
      for (int r = 0; r < 4; ++r) acc[r] = fmaf(distv, w4[r], b4[r]);
      #pragma unroll
      for (int ks = 0; ks < 4; ++ks)
        acc = __builtin_amdgcn_mfma_f32_16x16x32_bf16(a[ks], einB[ks], acc, 0, 0, 0);
      // C-layout: col = ln15 = edge, rows j = jt*16 + kg*4 + r
      uint2 uu;
      uu.x = cvt_pk(fsilu(acc[0]), fsilu(acc[1]));
      uu.y = cvt_pk(fsilu(acc[2]), fsilu(acc[3]));
      *(uint2*)&hLds[erow * HSTR + j * 16 + kg * 4] = uu;
    }
    // phase C partial: mac += h[e][k] * W2T over this half's k range
    const int nks = half ? 4 : 5;
    #pragma unroll 1
    for (int ksl = 0; ksl < nks; ++ksl) {
      const int kglob = half * 160 + ksl * 32;
      short8 ah = *(const short8*)&hLds[erow * HSTR + ksl * 32 + kg * 8];
      short8 w0 = *(const short8*)&W2T[ln15 * H1T + kglob + kg * 8];
      short8 w1 = *(const short8*)&W2T[(16 + ln15) * H1T + kglob + kg * 8];
      mac0 = __builtin_amdgcn_mfma_f32_16x16x32_bf16(ah, w0, mac0, 0, 0, 0);
      mac1 = __builtin_amdgcn_mfma_f32_16x16x32_bf16(ah, w1, mac1, 0, 0, 0);
    }
  }

  // m -> ml (LDS transpose within wave): col n = ln15(+16), row e = wid*16+kg*4+r
  #pragma unroll
  for (int r = 0; r < 4; ++r) {
    int e = wid * 16 + kg * 4 + r;
    ml[e * MLSTR + ln15] = f2bf(fsilu(mac0[r]));
    ml[e * MLSTR + 16 + ln15] = f2bf(fsilu(mac1[r]));
  }

  // ---- phase D: cw = tanh(sum_n silu(m @ cW1 + cb1)*cW2 + cb2) ----
  const unsigned short* CW1T = cw1t + layer * CH * MDIM;
  const float* CB1 = cb1 + layer * CH;
  const float* CW2v = cW2 + layer * CH;
  short8 am = *(const short8*)&ml[erow * MLSTR + kg * 8];
  float psum[4] = {0.f, 0.f, 0.f, 0.f};
  #pragma unroll
  for (int nt = 0; nt < 8; ++nt) {
    float cb = CB1[nt * 16 + ln15];
    f32x4 cacc = {cb, cb, cb, cb};
    short8 bc = *(const short8*)&CW1T[(nt * 16 + ln15) * MDIM + kg * 8];
    cacc = __builtin_amdgcn_mfma_f32_16x16x32_bf16(am, bc, cacc, 0, 0, 0);
    float w2v = CW2v[nt * 16 + ln15];
    #pragma unroll
    for (int r = 0; r < 4; ++r) psum[r] += fsilu(cacc[r]) * w2v;
  }
  // reduce over ln15 (butterfly leaves result in every lane of the 16-group)
  #pragma unroll
  for (int off = 1; off < 16; off <<= 1) {
    #pragma unroll
    for (int r = 0; r < 4; ++r) psum[r] += __shfl_xor(psum[r], off, 64);
  }
  // spread: lane j<16 gets cw-presum for edge wid*16+j (= psum[j&3] from kg=j>>2)
  float cwv = 0.0f;
  #pragma unroll
  for (int r = 0; r < 4; ++r) {
    float t = __shfl(psum[r], ((lane & 15) >> 2) * 16, 64);
    if ((lane & 3) == r) cwv = t;
  }

  // coalesced m_ij write: lane l writes 16B of edge wid*16+(l>>2)
  {
    int e_loc = lane >> 2, seg = lane & 3;
    short8 v = *(const short8*)&ml[(wid * 16 + e_loc) * MLSTR + seg * 8];
    *(short8*)&ms[(size_t)(e0 + wid * 16 + e_loc) * MDIM + seg * 8] = v;
  }
  if (lane < 16) {
    float cw = ftanh(cwv + cb2[layer]);
    float fac = cw * cscale[layer] / fmaxf(sqrtf(distv), 1e-8f);
    *(float4*)&mh4[(size_t)emine * 4] = make_float4(fac * rx, fac * ry, fac * rz, 0.0f);
  }
}

__global__ __launch_bounds__(256)
void gather_node_kernel(const float* __restrict__ Xin,
                        const unsigned short* __restrict__ ms,
                        const float* __restrict__ mh4,
                        const int* __restrict__ csr,
                        const float* __restrict__ nW1, const float* __restrict__ nb1,
                        const float* __restrict__ nW2, const float* __restrict__ nb2,
                        float* __restrict__ Xout, unsigned short* __restrict__ Xb,
                        int writeXb, int layer)
{
  __shared__ float nin[4][97];
  __shared__ float hn[4][NH + 1];
  __shared__ float mhs[4][3];
  const int tid = threadIdx.x;
  const int w = tid >> 6;
  const int lane = tid & 63;
  const int n = xcd_swz(blockIdx.x, gridDim.x) * 4 + w;

  const int off = csr[n];
  const int end = csr[n + 1];

  {
    const int col = lane & 31;
    const int hh = lane >> 5;
    float s = 0.0f;
    for (int r = off + hh; r < end; r += 2)
      s += bf2f(ms[(size_t)r * MDIM + col]);
    s += __shfl_xor(s, 32, 64);
    if (hh == 0) nin[w][FDIM + col] = s;
  }
  {
    const int mc = lane & 3;
    const int mr = lane >> 2;
    float t = 0.0f;
    for (int r = off + mr; r < end; r += 16)
      t += mh4[(size_t)r * 4 + mc];
    t += __shfl_xor(t, 4, 64);
    t += __shfl_xor(t, 8, 64);
    t += __shfl_xor(t, 16, 64);
    t += __shfl_xor(t, 32, 64);
    if (lane < 3) mhs[w][lane] = t;
  }
  nin[w][lane] = Xin[n * XDIM + PDIM + lane];
  __syncthreads();

  const float* W1 = nW1 + layer * (FDIM + MDIM) * NH;
  const float* B1 = nb1 + layer * NH;
  float a0 = B1[lane];
  float a1 = B1[lane + 64];
  #pragma unroll 4
  for (int k = 0; k < FDIM + MDIM; ++k) {
    float v = nin[w][k];
    a0 = fmaf(v, W1[k * NH + lane], a0);
    a1 = fmaf(v, W1[k * NH + lane + 64], a1);
  }
  hn[w][lane] = fsilu(a0);
  hn[w][lane + 64] = fsilu(a1);
  __syncthreads();

  const float* W2 = nW2 + layer * NH * FDIM;
  float acc = nb2[layer * FDIM + lane];
  #pragma unroll 4
  for (int k = 0; k < NH; ++k)
    acc = fmaf(hn[w][k], W2[k * FDIM + lane], acc);

  float feat = Xin[n * XDIM + PDIM + lane];
  float outv = feat + acc;
  Xout[n * XDIM + PDIM + lane] = outv;
  if (writeXb) Xb[n * 64 + lane] = f2bf(outv);
  if (lane < PDIM)
    Xout[n * XDIM + lane] = Xin[n * XDIM + lane] + mhs[w][lane];
}

extern "C" void kernel_launch(void* const* d_in, const int* in_sizes, int n_in,
                              void* d_out, int out_size, void* d_ws, size_t ws_size,
                              hipStream_t stream) {
  const float* x      = (const float*)d_in[0];
  const int*   ei     = (const int*)d_in[1];
  const float* eW1    = (const float*)d_in[2];
  const float* eb1    = (const float*)d_in[3];
  const float* eW2    = (const float*)d_in[4];
  const float* eb2    = (const float*)d_in[5];
  const float* cW1    = (const float*)d_in[6];
  const float* cb1    = (const float*)d_in[7];
  const float* cW2    = (const float*)d_in[8];
  const float* cb2    = (const float*)d_in[9];
  const float* nW1    = (const float*)d_in[10];
  const float* nb1    = (const float*)d_in[11];
  const float* nW2    = (const float*)d_in[12];
  const float* nb2    = (const float*)d_in[13];
  const float* cscale = (const float*)d_in[14];

  float* ws     = (float*)d_ws;
  float* X1     = ws;                                   // N*67 f32
  float* mh4    = X1 + N_NODES * XDIM;                  // E*4 f32
  int*   csr    = (int*)(mh4 + (size_t)N_EDGES * 4);    // N+4
  int*   cursor = csr + N_NODES + 4;                    // N
  int*   cnt    = cursor + N_NODES;                     // N
  int*   srcS   = cnt + N_NODES;                        // E
  int*   dstS   = srcS + N_EDGES;                       // E
  unsigned short* w1t  = (unsigned short*)(dstS + N_EDGES);
  unsigned short* w2t  = w1t + NLAYERS * H1T * W1T_K;
  unsigned short* cw1t = w2t + NLAYERS * MDIM * H1T;
  float* b1p = (float*)(cw1t + NLAYERS * CH * MDIM);
  float* wrp = b1p + NLAYERS * H1T;
  unsigned short* Xb = (unsigned short*)(wrp + NLAYERS * H1T);  // N*64 bf16
  unsigned short* ms = Xb + (size_t)N_NODES * 64;               // E*32 bf16

  hipMemsetAsync(cnt, 0, N_NODES * sizeof(int), stream);
  count_kernel<<<(N_EDGES + 255) / 256, 256, 0, stream>>>(ei, cnt);
  scan_kernel<<<1, 1024, 0, stream>>>(cnt, csr, cursor);
  rank_kernel<<<(N_EDGES + 255) / 256, 256, 0, stream>>>(ei, cursor, srcS, dstS);
  {
    const int total = NLAYERS * (H1T * W1T_K + MDIM * H1T + CH * MDIM + 2 * H1T);
    prep_weights<<<(total + 255) / 256, 256, 0, stream>>>(eW1, eW2, cW1, eb1,
                                                          w1t, w2t, cw1t, b1p, wrp);
  }
  convert_x<<<(N_NODES * 8 + 255) / 256, 256, 0, stream>>>(x, Xb);

  for (int l = 0; l < NLAYERS; ++l) {
    const float* Xin = (l == 0) ? x : X1;
    float* Xout = (l == 0) ? X1 : (float*)d_out;
    edge_mfma_kernel<<<N_EDGES / 64, 256, 0, stream>>>(
        Xin, Xb, srcS, dstS, w1t, b1p, wrp, w2t, eb2, cw1t, cb1, cW2, cb2, cscale,
        ms, mh4, l);
    gather_node_kernel<<<N_NODES / 4, 256, 0, stream>>>(
        Xin, ms, mh4, csr, nW1, nb1, nW2, nb2, Xout, Xb, (l == 0) ? 1 : 0, l);
  }
}

// Round 8
// 1172.489 us; speedup vs baseline: 1.0167x; 1.0167x over previous
//
#include <hip/hip_runtime.h>

#define N_NODES 50000
#define N_EDGES 800000
#define PDIM 3
#define FDIM 64
#define MDIM 32
#define NLAYERS 2
#define EINDIM 129
#define H1 258          // 2*EIN
#define CH 128          // 4*M
#define NH 128          // 2*F
#define XDIM 67         // P+F
#define H1T 288         // padded h dim (18 tiles of 16)
#define HSTR 168        // hLds col stride (bf16): 336B = 21 quanta (odd -> conflict-free b128)
#define W1T_K 136       // w1t k-dim (128 + 8 pad)
#define MLSTR 40        // ml LDS row stride (bf16)

typedef __attribute__((ext_vector_type(8))) short short8;
typedef __attribute__((ext_vector_type(4))) float f32x4;

#define LOG2E 1.4426950408889634f

__device__ __forceinline__ float fsilu(float x) {
  float e = __builtin_amdgcn_exp2f(-x * LOG2E);
  return x * __builtin_amdgcn_rcpf(1.0f + e);
}

__device__ __forceinline__ float ftanh(float x) {
  float xc = fminf(fmaxf(x, -15.0f), 15.0f);
  float E = __builtin_amdgcn_exp2f(2.0f * LOG2E * xc);
  return (E - 1.0f) * __builtin_amdgcn_rcpf(E + 1.0f);
}

__device__ __forceinline__ unsigned short f2bf(float f) {
  union { float f; unsigned u; } v; v.f = f;
  unsigned r = v.u + 0x7FFF + ((v.u >> 16) & 1);  // RNE
  return (unsigned short)(r >> 16);
}

__device__ __forceinline__ float bf2f(unsigned short u) {
  union { unsigned u; float f; } v; v.u = ((unsigned)u) << 16;
  return v.f;
}

__device__ __forceinline__ unsigned cvt_pk(float lo, float hi) {
  unsigned r;
  asm("v_cvt_pk_bf16_f32 %0, %1, %2" : "=v"(r) : "v"(lo), "v"(hi));
  return r;
}

// bijective XCD-chunk swizzle (m204)
__device__ __forceinline__ int xcd_swz(int bid, int nwg) {
  const int nx = 8;
  int q = nwg / nx, r = nwg % nx;
  int xcd = bid % nx, idx = bid / nx;
  return (xcd < r) ? xcd * (q + 1) + idx : r * (q + 1) + (xcd - r) * q + idx;
}

// ---- CSR build ----
__global__ void count_kernel(const int* __restrict__ ei, int* __restrict__ cnt) {
  int e = blockIdx.x * 256 + threadIdx.x;
  if (e < N_EDGES) atomicAdd(&cnt[ei[N_EDGES + e]], 1);
}

__global__ __launch_bounds__(1024)
void scan_kernel(const int* __restrict__ cnt, int* __restrict__ csr, int* __restrict__ cursor) {
  __shared__ int partial[1024];
  const int tid = threadIdx.x;
  const int CHUNK = 49;
  int base = tid * CHUNK;
  int s = 0;
  for (int i = 0; i < CHUNK; ++i) {
    int idx = base + i;
    if (idx < N_NODES) s += cnt[idx];
  }
  partial[tid] = s;
  __syncthreads();
  for (int off = 1; off < 1024; off <<= 1) {
    int v = (tid >= off) ? partial[tid - off] : 0;
    __syncthreads();
    partial[tid] += v;
    __syncthreads();
  }
  int run = partial[tid] - s;
  for (int i = 0; i < CHUNK; ++i) {
    int idx = base + i;
    if (idx < N_NODES) {
      csr[idx] = run;
      cursor[idx] = run;
      run += cnt[idx];
    }
  }
  if (tid == 1023) csr[N_NODES] = run;
}

// sort edges by dst: slot p gets (src, dst)
__global__ void rank_kernel(const int* __restrict__ ei, int* __restrict__ cursor,
                            int* __restrict__ srcS, int* __restrict__ dstS) {
  int e = blockIdx.x * 256 + threadIdx.x;
  if (e < N_EDGES) {
    int s = ei[e];
    int d = ei[N_EDGES + e];
    int p = atomicAdd(&cursor[d], 1);
    srcS[p] = s;
    dstS[p] = d;
  }
}

// ---- weight prep ----
__global__ void prep_weights(const float* __restrict__ eW1, const float* __restrict__ eW2,
                             const float* __restrict__ cW1, const float* __restrict__ eb1,
                             unsigned short* __restrict__ w1t, unsigned short* __restrict__ w2t,
                             unsigned short* __restrict__ cw1t,
                             float* __restrict__ b1p, float* __restrict__ wrp) {
  int idx = blockIdx.x * 256 + threadIdx.x;
  const int n1 = NLAYERS * H1T * W1T_K;
  const int n2 = NLAYERS * MDIM * H1T;
  const int n3 = NLAYERS * CH * MDIM;
  const int n4 = NLAYERS * H1T;
  if (idx < n1) {
    int k = idx % W1T_K;
    int rest = idx / W1T_K;
    int j = rest % H1T;
    int l = rest / H1T;
    float v = (k < 128 && j < H1) ? eW1[(l * EINDIM + k) * H1 + j] : 0.0f;
    w1t[idx] = f2bf(v);
  } else if (idx < n1 + n2) {
    int t = idx - n1;
    int k = t % H1T;
    int rest = t / H1T;
    int n = rest % MDIM;
    int l = rest / MDIM;
    float v = (k < H1) ? eW2[(l * H1 + k) * MDIM + n] : 0.0f;
    w2t[t] = f2bf(v);
  } else if (idx < n1 + n2 + n3) {
    int t = idx - n1 - n2;
    int k = t % MDIM;
    int rest = t / MDIM;
    int n = rest % CH;
    int l = rest / CH;
    cw1t[t] = f2bf(cW1[(l * MDIM + k) * CH + n]);
  } else if (idx < n1 + n2 + n3 + n4) {
    int t = idx - n1 - n2 - n3;
    int j = t % H1T;
    int l = t / H1T;
    b1p[t] = (j < H1) ? eb1[l * H1 + j] : 0.0f;
  } else if (idx < n1 + n2 + n3 + 2 * n4) {
    int t = idx - n1 - n2 - n3 - n4;
    int j = t % H1T;
    int l = t / H1T;
    wrp[t] = (j < H1) ? eW1[((size_t)l * EINDIM + 128) * H1 + j] : 0.0f;
  }
}

// convert X features to bf16 [N][64]
__global__ void convert_x(const float* __restrict__ X, unsigned short* __restrict__ Xb) {
  int idx = blockIdx.x * 256 + threadIdx.x;
  if (idx >= N_NODES * 8) return;
  int n = idx >> 3, c = idx & 7;
  const float* src = X + n * XDIM + PDIM + c * 8;
  short8 v;
  #pragma unroll
  for (int i = 0; i < 8; ++i) v[i] = (short)f2bf(src[i]);
  *(short8*)&Xb[n * 64 + c * 8] = v;
}

// Wave-owned edge kernel, sorted edges, no __syncthreads.
// launch_bounds(256,5): ~100 VGPR budget so the compiler can pipeline
// (R7's (256,6) gave VGPR=40 and a latency-bound kernel).
__global__ __launch_bounds__(256, 5)
void edge_mfma_kernel(const float* __restrict__ X,
                      const unsigned short* __restrict__ Xb,
                      const int* __restrict__ srcS, const int* __restrict__ dstS,
                      const unsigned short* __restrict__ w1t,
                      const float* __restrict__ b1p, const float* __restrict__ wrp,
                      const unsigned short* __restrict__ w2t, const float* __restrict__ eb2,
                      const unsigned short* __restrict__ cw1t, const float* __restrict__ cb1,
                      const float* __restrict__ cW2, const float* __restrict__ cb2,
                      const float* __restrict__ cscale,
                      unsigned short* __restrict__ ms, float* __restrict__ mh4,
                      int layer)
{
  __shared__ unsigned short hLds[64 * HSTR];   // 21504 B
  __shared__ unsigned short ml[64 * MLSTR];    //  5120 B

  const int tid = threadIdx.x;
  const int lane = tid & 63;
  const int wid = tid >> 6;
  const int ln15 = lane & 15;
  const int kg = lane >> 4;
  const int e0 = xcd_swz(blockIdx.x, gridDim.x) * 64;
  const int emine = e0 + wid * 16 + ln15;
  const int erow = wid * 16 + ln15;

  const int ns = srcS[emine];
  const int nd = dstS[emine];
  float rx = X[ns * XDIM + 0] - X[nd * XDIM + 0];
  float ry = X[ns * XDIM + 1] - X[nd * XDIM + 1];
  float rz = X[ns * XDIM + 2] - X[nd * XDIM + 2];
  const float distv = rx * rx + ry * ry + rz * rz;

  short8 einB[4];
  #pragma unroll
  for (int ks = 0; ks < 4; ++ks) {
    int node = (ks < 2) ? nd : ns;
    einB[ks] = *(const short8*)&Xb[node * 64 + (ks & 1) * 32 + kg * 8];
  }

  const unsigned short* W1T = w1t + layer * H1T * W1T_K;
  const float* B1P = b1p + layer * H1T;
  const float* WRP = wrp + layer * H1T;
  const unsigned short* W2T = w2t + layer * MDIM * H1T;
  const float* B2 = eb2 + layer * MDIM;

  float b20 = B2[ln15], b21 = B2[16 + ln15];
  f32x4 mac0 = {b20, b20, b20, b20};
  f32x4 mac1 = {b21, b21, b21, b21};

  // ---- phases B+C in two k-halves (10 + 8 j-tiles), hLds reused ----
  #pragma unroll 1
  for (int half = 0; half < 2; ++half) {
    const int jt0 = half ? 10 : 0;
    const int njt = half ? 8 : 10;
    // phase B: unroll 2 -> 2 independent acc chains, 8 A-loads in flight
    #pragma unroll 2
    for (int j = 0; j < njt; ++j) {
      const int jt = jt0 + j;
      f32x4 b4 = *(const f32x4*)&B1P[jt * 16 + kg * 4];
      f32x4 w4 = *(const f32x4*)&WRP[jt * 16 + kg * 4];
      short8 a[4];
      #pragma unroll
      for (int ks = 0; ks < 4; ++ks)
        a[ks] = *(const short8*)&W1T[(jt * 16 + ln15) * W1T_K + ks * 32 + kg * 8];
      f32x4 acc;
      #pragma unroll
      for (int r = 0; r < 4; ++r) acc[r] = fmaf(distv, w4[r], b4[r]);
      #pragma unroll
      for (int ks = 0; ks < 4; ++ks)
        acc = __builtin_amdgcn_mfma_f32_16x16x32_bf16(a[ks], einB[ks], acc, 0, 0, 0);
      uint2 uu;
      uu.x = cvt_pk(fsilu(acc[0]), fsilu(acc[1]));
      uu.y = cvt_pk(fsilu(acc[2]), fsilu(acc[3]));
      *(uint2*)&hLds[erow * HSTR + j * 16 + kg * 4] = uu;
    }
    // phase C partial over this half's k range (2 independent chains)
    const int nks = half ? 4 : 5;
    #pragma unroll 2
    for (int ksl = 0; ksl < nks; ++ksl) {
      const int kglob = half * 160 + ksl * 32;
      short8 ah = *(const short8*)&hLds[erow * HSTR + ksl * 32 + kg * 8];
      short8 w0 = *(const short8*)&W2T[ln15 * H1T + kglob + kg * 8];
      short8 w1 = *(const short8*)&W2T[(16 + ln15) * H1T + kglob + kg * 8];
      mac0 = __builtin_amdgcn_mfma_f32_16x16x32_bf16(ah, w0, mac0, 0, 0, 0);
      mac1 = __builtin_amdgcn_mfma_f32_16x16x32_bf16(ah, w1, mac1, 0, 0, 0);
    }
  }

  // m -> ml (wave-local LDS transpose)
  #pragma unroll
  for (int r = 0; r < 4; ++r) {
    int e = wid * 16 + kg * 4 + r;
    ml[e * MLSTR + ln15] = f2bf(fsilu(mac0[r]));
    ml[e * MLSTR + 16 + ln15] = f2bf(fsilu(mac1[r]));
  }

  // ---- phase D ----
  const unsigned short* CW1T = cw1t + layer * CH * MDIM;
  const float* CB1 = cb1 + layer * CH;
  const float* CW2v = cW2 + layer * CH;
  short8 am = *(const short8*)&ml[erow * MLSTR + kg * 8];
  float psum[4] = {0.f, 0.f, 0.f, 0.f};
  #pragma unroll
  for (int nt = 0; nt < 8; ++nt) {
    float cb = CB1[nt * 16 + ln15];
    f32x4 cacc = {cb, cb, cb, cb};
    short8 bc = *(const short8*)&CW1T[(nt * 16 + ln15) * MDIM + kg * 8];
    cacc = __builtin_amdgcn_mfma_f32_16x16x32_bf16(am, bc, cacc, 0, 0, 0);
    float w2v = CW2v[nt * 16 + ln15];
    #pragma unroll
    for (int r = 0; r < 4; ++r) psum[r] += fsilu(cacc[r]) * w2v;
  }
  #pragma unroll
  for (int off = 1; off < 16; off <<= 1) {
    #pragma unroll
    for (int r = 0; r < 4; ++r) psum[r] += __shfl_xor(psum[r], off, 64);
  }
  float cwv = 0.0f;
  #pragma unroll
  for (int r = 0; r < 4; ++r) {
    float t = __shfl(psum[r], ((lane & 15) >> 2) * 16, 64);
    if ((lane & 3) == r) cwv = t;
  }

  // coalesced linear m_ij write
  {
    int e_loc = lane >> 2, seg = lane & 3;
    short8 v = *(const short8*)&ml[(wid * 16 + e_loc) * MLSTR + seg * 8];
    *(short8*)&ms[(size_t)(e0 + wid * 16 + e_loc) * MDIM + seg * 8] = v;
  }
  if (lane < 16) {
    float cw = ftanh(cwv + cb2[layer]);
    float fac = cw * cscale[layer] / fmaxf(sqrtf(distv), 1e-8f);
    *(float4*)&mh4[(size_t)emine * 4] = make_float4(fac * rx, fac * ry, fac * rz, 0.0f);
  }
}

__global__ __launch_bounds__(256)
void gather_node_kernel(const float* __restrict__ Xin,
                        const unsigned short* __restrict__ ms,
                        const float* __restrict__ mh4,
                        const int* __restrict__ csr,
                        const float* __restrict__ nW1, const float* __restrict__ nb1,
                        const float* __restrict__ nW2, const float* __restrict__ nb2,
                        float* __restrict__ Xout, unsigned short* __restrict__ Xb,
                        int writeXb, int layer)
{
  __shared__ float nin[4][97];
  __shared__ float hn[4][NH + 1];
  __shared__ float mhs[4][3];
  const int tid = threadIdx.x;
  const int w = tid >> 6;
  const int lane = tid & 63;
  const int n = xcd_swz(blockIdx.x, gridDim.x) * 4 + w;

  const int off = csr[n];
  const int end = csr[n + 1];

  // m_i gather: lane = (rowgrp = lane>>4, colpair = lane&15); 4 rows/iter, uint loads
  {
    float s0 = 0.0f, s1 = 0.0f;
    for (int r = off + (lane >> 4); r < end; r += 4) {
      unsigned u = *(const unsigned*)&ms[(size_t)r * MDIM + (lane & 15) * 2];
      union { unsigned u; float f; } lo, hi;
      lo.u = u << 16;
      hi.u = u & 0xFFFF0000u;
      s0 += lo.f;
      s1 += hi.f;
    }
    s0 += __shfl_xor(s0, 16, 64);
    s1 += __shfl_xor(s1, 16, 64);
    s0 += __shfl_xor(s0, 32, 64);
    s1 += __shfl_xor(s1, 32, 64);
    if (lane < 16) {
      nin[w][FDIM + lane * 2] = s0;
      nin[w][FDIM + lane * 2 + 1] = s1;
    }
  }
  // mhat_i gather
  {
    const int mc = lane & 3;
    const int mr = lane >> 2;
    float t = 0.0f;
    for (int r = off + mr; r < end; r += 16)
      t += mh4[(size_t)r * 4 + mc];
    t += __shfl_xor(t, 4, 64);
    t += __shfl_xor(t, 8, 64);
    t += __shfl_xor(t, 16, 64);
    t += __shfl_xor(t, 32, 64);
    if (lane < 3) mhs[w][lane] = t;
  }
  nin[w][lane] = Xin[n * XDIM + PDIM + lane];
  __syncthreads();

  const float* W1 = nW1 + layer * (FDIM + MDIM) * NH;
  const float* B1 = nb1 + layer * NH;
  float a0 = B1[lane];
  float a1 = B1[lane + 64];
  #pragma unroll 4
  for (int k = 0; k < FDIM + MDIM; ++k) {
    float v = nin[w][k];
    a0 = fmaf(v, W1[k * NH + lane], a0);
    a1 = fmaf(v, W1[k * NH + lane + 64], a1);
  }
  hn[w][lane] = fsilu(a0);
  hn[w][lane + 64] = fsilu(a1);
  __syncthreads();

  const float* W2 = nW2 + layer * NH * FDIM;
  float acc = nb2[layer * FDIM + lane];
  #pragma unroll 4
  for (int k = 0; k < NH; ++k)
    acc = fmaf(hn[w][k], W2[k * FDIM + lane], acc);

  float feat = Xin[n * XDIM + PDIM + lane];
  float outv = feat + acc;
  Xout[n * XDIM + PDIM + lane] = outv;
  if (writeXb) Xb[n * 64 + lane] = f2bf(outv);
  if (lane < PDIM)
    Xout[n * XDIM + lane] = Xin[n * XDIM + lane] + mhs[w][lane];
}

extern "C" void kernel_launch(void* const* d_in, const int* in_sizes, int n_in,
                              void* d_out, int out_size, void* d_ws, size_t ws_size,
                              hipStream_t stream) {
  const float* x      = (const float*)d_in[0];
  const int*   ei     = (const int*)d_in[1];
  const float* eW1    = (const float*)d_in[2];
  const float* eb1    = (const float*)d_in[3];
  const float* eW2    = (const float*)d_in[4];
  const float* eb2    = (const float*)d_in[5];
  const float* cW1    = (const float*)d_in[6];
  const float* cb1    = (const float*)d_in[7];
  const float* cW2    = (const float*)d_in[8];
  const float* cb2    = (const float*)d_in[9];
  const float* nW1    = (const float*)d_in[10];
  const float* nb1    = (const float*)d_in[11];
  const float* nW2    = (const float*)d_in[12];
  const float* nb2    = (const float*)d_in[13];
  const float* cscale = (const float*)d_in[14];

  float* ws     = (float*)d_ws;
  float* X1     = ws;                                   // N*67 f32
  float* mh4    = X1 + N_NODES * XDIM;                  // E*4 f32
  int*   csr    = (int*)(mh4 + (size_t)N_EDGES * 4);    // N+4
  int*   cursor = csr + N_NODES + 4;                    // N
  int*   cnt    = cursor + N_NODES;                     // N
  int*   srcS   = cnt + N_NODES;                        // E
  int*   dstS   = srcS + N_EDGES;                       // E
  unsigned short* w1t  = (unsigned short*)(dstS + N_EDGES);
  unsigned short* w2t  = w1t + NLAYERS * H1T * W1T_K;
  unsigned short* cw1t = w2t + NLAYERS * MDIM * H1T;
  float* b1p = (float*)(cw1t + NLAYERS * CH * MDIM);
  float* wrp = b1p + NLAYERS * H1T;
  unsigned short* Xb = (unsigned short*)(wrp + NLAYERS * H1T);  // N*64 bf16
  unsigned short* ms = Xb + (size_t)N_NODES * 64;               // E*32 bf16

  hipMemsetAsync(cnt, 0, N_NODES * sizeof(int), stream);
  count_kernel<<<(N_EDGES + 255) / 256, 256, 0, stream>>>(ei, cnt);
  scan_kernel<<<1, 1024, 0, stream>>>(cnt, csr, cursor);
  rank_kernel<<<(N_EDGES + 255) / 256, 256, 0, stream>>>(ei, cursor, srcS, dstS);
  {
    const int total = NLAYERS * (H1T * W1T_K + MDIM * H1T + CH * MDIM + 2 * H1T);
    prep_weights<<<(total + 255) / 256, 256, 0, stream>>>(eW1, eW2, cW1, eb1,
                                                          w1t, w2t, cw1t, b1p, wrp);
  }
  convert_x<<<(N_NODES * 8 + 255) / 256, 256, 0, stream>>>(x, Xb);

  for (int l = 0; l < NLAYERS; ++l) {
    const float* Xin = (l == 0) ? x : X1;
    float* Xout = (l == 0) ? X1 : (float*)d_out;
    edge_mfma_kernel<<<N_EDGES / 64, 256, 0, stream>>>(
        Xin, Xb, srcS, dstS, w1t, b1p, wrp, w2t, eb2, cw1t, cb1, cW2, cb2, cscale,
        ms, mh4, l);
    gather_node_kernel<<<N_NODES / 4, 256, 0, stream>>>(
        Xin, ms, mh4, csr, nW1, nb1, nW2, nb2, Xout, Xb, (l == 0) ? 1 : 0, l);
  }
}

// Round 9
// 1055.863 us; speedup vs baseline: 1.1290x; 1.1105x over previous
//
#include <hip/hip_runtime.h>

#define N_NODES 50000
#define N_EDGES 800000
#define PDIM 3
#define FDIM 64
#define MDIM 32
#define NLAYERS 2
#define EINDIM 129
#define H1 258          // 2*EIN
#define CH 128          // 4*M
#define NH 128          // 2*F
#define XDIM 67         // P+F
#define H1T 288         // padded h dim (18 tiles of 16)
#define HSTR 168        // hLds col stride (bf16): 336B (2-way on b64/b128: free)
#define W1T_K 136       // w1t k-dim (128 + 8 pad)
#define MLSTR 40        // ml LDS row stride (bf16)

typedef __attribute__((ext_vector_type(8))) short short8;
typedef __attribute__((ext_vector_type(4))) float f32x4;

#define LOG2E 1.4426950408889634f

__device__ __forceinline__ float fsilu(float x) {
  float e = __builtin_amdgcn_exp2f(-x * LOG2E);
  return x * __builtin_amdgcn_rcpf(1.0f + e);
}

__device__ __forceinline__ float ftanh(float x) {
  float xc = fminf(fmaxf(x, -15.0f), 15.0f);
  float E = __builtin_amdgcn_exp2f(2.0f * LOG2E * xc);
  return (E - 1.0f) * __builtin_amdgcn_rcpf(E + 1.0f);
}

__device__ __forceinline__ unsigned short f2bf(float f) {
  union { float f; unsigned u; } v; v.f = f;
  unsigned r = v.u + 0x7FFF + ((v.u >> 16) & 1);  // RNE
  return (unsigned short)(r >> 16);
}

__device__ __forceinline__ float bf2f(unsigned short u) {
  union { unsigned u; float f; } v; v.u = ((unsigned)u) << 16;
  return v.f;
}

__device__ __forceinline__ unsigned cvt_pk(float lo, float hi) {
  unsigned r;
  asm("v_cvt_pk_bf16_f32 %0, %1, %2" : "=v"(r) : "v"(lo), "v"(hi));
  return r;
}

// bijective XCD-chunk swizzle (m204)
__device__ __forceinline__ int xcd_swz(int bid, int nwg) {
  const int nx = 8;
  int q = nwg / nx, r = nwg % nx;
  int xcd = bid % nx, idx = bid / nx;
  return (xcd < r) ? xcd * (q + 1) + idx : r * (q + 1) + (xcd - r) * q + idx;
}

// ---- CSR build ----
__global__ void count_kernel(const int* __restrict__ ei, int* __restrict__ cnt) {
  int e = blockIdx.x * 256 + threadIdx.x;
  if (e < N_EDGES) atomicAdd(&cnt[ei[N_EDGES + e]], 1);
}

__global__ __launch_bounds__(1024)
void scan_kernel(const int* __restrict__ cnt, int* __restrict__ csr, int* __restrict__ cursor) {
  __shared__ int partial[1024];
  const int tid = threadIdx.x;
  const int CHUNK = 49;
  int base = tid * CHUNK;
  int s = 0;
  for (int i = 0; i < CHUNK; ++i) {
    int idx = base + i;
    if (idx < N_NODES) s += cnt[idx];
  }
  partial[tid] = s;
  __syncthreads();
  for (int off = 1; off < 1024; off <<= 1) {
    int v = (tid >= off) ? partial[tid - off] : 0;
    __syncthreads();
    partial[tid] += v;
    __syncthreads();
  }
  int run = partial[tid] - s;
  for (int i = 0; i < CHUNK; ++i) {
    int idx = base + i;
    if (idx < N_NODES) {
      csr[idx] = run;
      cursor[idx] = run;
      run += cnt[idx];
    }
  }
  if (tid == 1023) csr[N_NODES] = run;
}

// sort edges by dst: slot p gets (src, dst)
__global__ void rank_kernel(const int* __restrict__ ei, int* __restrict__ cursor,
                            int* __restrict__ srcS, int* __restrict__ dstS) {
  int e = blockIdx.x * 256 + threadIdx.x;
  if (e < N_EDGES) {
    int s = ei[e];
    int d = ei[N_EDGES + e];
    int p = atomicAdd(&cursor[d], 1);
    srcS[p] = s;
    dstS[p] = d;
  }
}

// ---- weight prep ----
__global__ void prep_weights(const float* __restrict__ eW1, const float* __restrict__ eW2,
                             const float* __restrict__ cW1, const float* __restrict__ eb1,
                             unsigned short* __restrict__ w1t, unsigned short* __restrict__ w2t,
                             unsigned short* __restrict__ cw1t,
                             float* __restrict__ b1p, float* __restrict__ wrp) {
  int idx = blockIdx.x * 256 + threadIdx.x;
  const int n1 = NLAYERS * H1T * W1T_K;
  const int n2 = NLAYERS * MDIM * H1T;
  const int n3 = NLAYERS * CH * MDIM;
  const int n4 = NLAYERS * H1T;
  if (idx < n1) {
    int k = idx % W1T_K;
    int rest = idx / W1T_K;
    int j = rest % H1T;
    int l = rest / H1T;
    float v = (k < 128 && j < H1) ? eW1[(l * EINDIM + k) * H1 + j] : 0.0f;
    w1t[idx] = f2bf(v);
  } else if (idx < n1 + n2) {
    int t = idx - n1;
    int k = t % H1T;
    int rest = t / H1T;
    int n = rest % MDIM;
    int l = rest / MDIM;
    float v = (k < H1) ? eW2[(l * H1 + k) * MDIM + n] : 0.0f;
    w2t[t] = f2bf(v);
  } else if (idx < n1 + n2 + n3) {
    int t = idx - n1 - n2;
    int k = t % MDIM;
    int rest = t / MDIM;
    int n = rest % CH;
    int l = rest / CH;
    cw1t[t] = f2bf(cW1[(l * MDIM + k) * CH + n]);
  } else if (idx < n1 + n2 + n3 + n4) {
    int t = idx - n1 - n2 - n3;
    int j = t % H1T;
    int l = t / H1T;
    b1p[t] = (j < H1) ? eb1[l * H1 + j] : 0.0f;
  } else if (idx < n1 + n2 + n3 + 2 * n4) {
    int t = idx - n1 - n2 - n3 - n4;
    int j = t % H1T;
    int l = t / H1T;
    wrp[t] = (j < H1) ? eW1[((size_t)l * EINDIM + 128) * H1 + j] : 0.0f;
  }
}

// convert X features to bf16 [N][64]
__global__ void convert_x(const float* __restrict__ X, unsigned short* __restrict__ Xb) {
  int idx = blockIdx.x * 256 + threadIdx.x;
  if (idx >= N_NODES * 8) return;
  int n = idx >> 3, c = idx & 7;
  const float* src = X + n * XDIM + PDIM + c * 8;
  short8 v;
  #pragma unroll
  for (int i = 0; i < 8; ++i) v[i] = (short)f2bf(src[i]);
  *(short8*)&Xb[n * 64 + c * 8] = v;
}

// Hybrid edge kernel: R6's j-split phase B (1 A-load -> 4 MFMA chains) +
// sorted edges (linear writes) + half-split h LDS (28.5KB -> 4 blocks/CU).
__global__ __launch_bounds__(256, 4)
void edge_mfma_kernel(const float* __restrict__ X,
                      const unsigned short* __restrict__ Xb,
                      const int* __restrict__ srcS, const int* __restrict__ dstS,
                      const unsigned short* __restrict__ w1t,
                      const float* __restrict__ b1p, const float* __restrict__ wrp,
                      const unsigned short* __restrict__ w2t, const float* __restrict__ eb2,
                      const unsigned short* __restrict__ cw1t, const float* __restrict__ cb1,
                      const float* __restrict__ cW2, const float* __restrict__ cb2,
                      const float* __restrict__ cscale,
                      unsigned short* __restrict__ ms, float* __restrict__ mh4,
                      int layer)
{
  __shared__ unsigned short hLds[64 * HSTR];   // 21504 B, row = edge, col = local j
  __shared__ unsigned short ml[64 * MLSTR];    //  5120 B
  __shared__ float distLds[64];
  __shared__ float rel3[64 * 3];
  __shared__ int sdS[64], sdD[64];

  const int tid = threadIdx.x;
  const int lane = tid & 63;
  const int wid = tid >> 6;
  const int ln15 = lane & 15;
  const int kg = lane >> 4;
  const int e0 = xcd_swz(blockIdx.x, gridDim.x) * 64;
  const int erow = wid * 16 + ln15;   // own edge row for phases C/D

  if (tid < 64) {
    int s = srcS[e0 + tid];
    int d = dstS[e0 + tid];
    sdS[tid] = s; sdD[tid] = d;
    float rx = X[s * XDIM + 0] - X[d * XDIM + 0];
    float ry = X[s * XDIM + 1] - X[d * XDIM + 1];
    float rz = X[s * XDIM + 2] - X[d * XDIM + 2];
    rel3[tid * 3 + 0] = rx;
    rel3[tid * 3 + 1] = ry;
    rel3[tid * 3 + 2] = rz;
    distLds[tid] = rx * rx + ry * ry + rz * rz;
  }
  __syncthreads();

  // einB for all 4 edge-tiles (every wave; redundant but L1/L2-hot with sorted dst)
  short8 einB[4][4];
  float distE[4];
  #pragma unroll
  for (int et = 0; et < 4; ++et) {
    int e = et * 16 + ln15;
    int nd = sdD[e], nsr = sdS[e];
    distE[et] = distLds[e];
    #pragma unroll
    for (int ks = 0; ks < 4; ++ks) {
      int node = (ks < 2) ? nd : nsr;
      einB[et][ks] = *(const short8*)&Xb[node * 64 + (ks & 1) * 32 + kg * 8];
    }
  }

  const unsigned short* W1T = w1t + layer * H1T * W1T_K;
  const float* B1P = b1p + layer * H1T;
  const float* WRP = wrp + layer * H1T;
  const unsigned short* W2T = w2t + layer * MDIM * H1T;
  const float* B2 = eb2 + layer * MDIM;

  float b20 = B2[ln15], b21 = B2[16 + ln15];
  f32x4 mac0 = {b20, b20, b20, b20};
  f32x4 mac1 = {b21, b21, b21, b21};

  #pragma unroll 1
  for (int half = 0; half < 2; ++half) {
    const int jt0 = half ? 10 : 0;
    const int njt = half ? 8 : 10;
    // ---- phase B: waves split j-tiles; one A-load feeds 4 MFMA chains ----
    for (int jl = wid; jl < njt; jl += 4) {
      const int jt = jt0 + jl;
      f32x4 b4 = *(const f32x4*)&B1P[jt * 16 + kg * 4];
      f32x4 w4 = *(const f32x4*)&WRP[jt * 16 + kg * 4];
      short8 a[4];
      #pragma unroll
      for (int ks = 0; ks < 4; ++ks)
        a[ks] = *(const short8*)&W1T[(jt * 16 + ln15) * W1T_K + ks * 32 + kg * 8];
      #pragma unroll
      for (int et = 0; et < 4; ++et) {
        f32x4 acc;
        #pragma unroll
        for (int r = 0; r < 4; ++r) acc[r] = fmaf(distE[et], w4[r], b4[r]);
        #pragma unroll
        for (int ks = 0; ks < 4; ++ks)
          acc = __builtin_amdgcn_mfma_f32_16x16x32_bf16(a[ks], einB[et][ks], acc, 0, 0, 0);
        // C-layout: col = ln15 = edge (tile et), rows j = jt*16 + kg*4 + r
        uint2 uu;
        uu.x = cvt_pk(fsilu(acc[0]), fsilu(acc[1]));
        uu.y = cvt_pk(fsilu(acc[2]), fsilu(acc[3]));
        *(uint2*)&hLds[(et * 16 + ln15) * HSTR + jl * 16 + kg * 4] = uu;
      }
    }
    __syncthreads();

    // ---- phase C partial: own 16 edges, this half's k range ----
    const int nks = half ? 4 : 5;
    #pragma unroll
    for (int ksl = 0; ksl < nks; ++ksl) {
      const int kglob = half * 160 + ksl * 32;
      short8 ah = *(const short8*)&hLds[erow * HSTR + ksl * 32 + kg * 8];
      short8 w0 = *(const short8*)&W2T[ln15 * H1T + kglob + kg * 8];
      short8 w1 = *(const short8*)&W2T[(16 + ln15) * H1T + kglob + kg * 8];
      mac0 = __builtin_amdgcn_mfma_f32_16x16x32_bf16(ah, w0, mac0, 0, 0, 0);
      mac1 = __builtin_amdgcn_mfma_f32_16x16x32_bf16(ah, w1, mac1, 0, 0, 0);
    }
    if (half == 0) __syncthreads();  // protect hLds before overwrite
  }

  // m -> ml (wave-local LDS transpose)
  #pragma unroll
  for (int r = 0; r < 4; ++r) {
    int e = wid * 16 + kg * 4 + r;
    ml[e * MLSTR + ln15] = f2bf(fsilu(mac0[r]));
    ml[e * MLSTR + 16 + ln15] = f2bf(fsilu(mac1[r]));
  }

  // ---- phase D: cw = tanh(sum_n silu(m @ cW1 + cb1)*cW2 + cb2) ----
  const unsigned short* CW1T = cw1t + layer * CH * MDIM;
  const float* CB1 = cb1 + layer * CH;
  const float* CW2v = cW2 + layer * CH;
  short8 am = *(const short8*)&ml[erow * MLSTR + kg * 8];
  float psum[4] = {0.f, 0.f, 0.f, 0.f};
  #pragma unroll
  for (int nt = 0; nt < 8; ++nt) {
    float cb = CB1[nt * 16 + ln15];
    f32x4 cacc = {cb, cb, cb, cb};
    short8 bc = *(const short8*)&CW1T[(nt * 16 + ln15) * MDIM + kg * 8];
    cacc = __builtin_amdgcn_mfma_f32_16x16x32_bf16(am, bc, cacc, 0, 0, 0);
    float w2v = CW2v[nt * 16 + ln15];
    #pragma unroll
    for (int r = 0; r < 4; ++r) psum[r] += fsilu(cacc[r]) * w2v;
  }
  #pragma unroll
  for (int off = 1; off < 16; off <<= 1) {
    #pragma unroll
    for (int r = 0; r < 4; ++r) psum[r] += __shfl_xor(psum[r], off, 64);
  }
  float cwv = 0.0f;
  #pragma unroll
  for (int r = 0; r < 4; ++r) {
    float t = __shfl(psum[r], ((lane & 15) >> 2) * 16, 64);
    if ((lane & 3) == r) cwv = t;
  }

  // coalesced linear m_ij write
  {
    int e_loc = lane >> 2, seg = lane & 3;
    short8 v = *(const short8*)&ml[(wid * 16 + e_loc) * MLSTR + seg * 8];
    *(short8*)&ms[(size_t)(e0 + wid * 16 + e_loc) * MDIM + seg * 8] = v;
  }
  if (lane < 16) {
    int eg = e0 + erow;
    float cw = ftanh(cwv + cb2[layer]);
    float fac = cw * cscale[layer] / fmaxf(sqrtf(distLds[erow]), 1e-8f);
    *(float4*)&mh4[(size_t)eg * 4] =
        make_float4(fac * rel3[erow * 3 + 0], fac * rel3[erow * 3 + 1],
                    fac * rel3[erow * 3 + 2], 0.0f);
  }
}

__global__ __launch_bounds__(256)
void gather_node_kernel(const float* __restrict__ Xin,
                        const unsigned short* __restrict__ ms,
                        const float* __restrict__ mh4,
                        const int* __restrict__ csr,
                        const float* __restrict__ nW1, const float* __restrict__ nb1,
                        const float* __restrict__ nW2, const float* __restrict__ nb2,
                        float* __restrict__ Xout, unsigned short* __restrict__ Xb,
                        int writeXb, int layer)
{
  __shared__ float nin[4][97];
  __shared__ float hn[4][NH + 1];
  __shared__ float mhs[4][3];
  const int tid = threadIdx.x;
  const int w = tid >> 6;
  const int lane = tid & 63;
  const int n = xcd_swz(blockIdx.x, gridDim.x) * 4 + w;

  const int off = csr[n];
  const int end = csr[n + 1];

  // m_i gather: 4 rows/iter, uint loads
  {
    float s0 = 0.0f, s1 = 0.0f;
    for (int r = off + (lane >> 4); r < end; r += 4) {
      unsigned u = *(const unsigned*)&ms[(size_t)r * MDIM + (lane & 15) * 2];
      union { unsigned u; float f; } lo, hi;
      lo.u = u << 16;
      hi.u = u & 0xFFFF0000u;
      s0 += lo.f;
      s1 += hi.f;
    }
    s0 += __shfl_xor(s0, 16, 64);
    s1 += __shfl_xor(s1, 16, 64);
    s0 += __shfl_xor(s0, 32, 64);
    s1 += __shfl_xor(s1, 32, 64);
    if (lane < 16) {
      nin[w][FDIM + lane * 2] = s0;
      nin[w][FDIM + lane * 2 + 1] = s1;
    }
  }
  // mhat_i gather
  {
    const int mc = lane & 3;
    const int mr = lane >> 2;
    float t = 0.0f;
    for (int r = off + mr; r < end; r += 16)
      t += mh4[(size_t)r * 4 + mc];
    t += __shfl_xor(t, 4, 64);
    t += __shfl_xor(t, 8, 64);
    t += __shfl_xor(t, 16, 64);
    t += __shfl_xor(t, 32, 64);
    if (lane < 3) mhs[w][lane] = t;
  }
  nin[w][lane] = Xin[n * XDIM + PDIM + lane];
  __syncthreads();

  const float* W1 = nW1 + layer * (FDIM + MDIM) * NH;
  const float* B1 = nb1 + layer * NH;
  float a0 = B1[lane];
  float a1 = B1[lane + 64];
  #pragma unroll 4
  for (int k = 0; k < FDIM + MDIM; ++k) {
    float v = nin[w][k];
    a0 = fmaf(v, W1[k * NH + lane], a0);
    a1 = fmaf(v, W1[k * NH + lane + 64], a1);
  }
  hn[w][lane] = fsilu(a0);
  hn[w][lane + 64] = fsilu(a1);
  __syncthreads();

  const float* W2 = nW2 + layer * NH * FDIM;
  float acc = nb2[layer * FDIM + lane];
  #pragma unroll 4
  for (int k = 0; k < NH; ++k)
    acc = fmaf(hn[w][k], W2[k * FDIM + lane], acc);

  float feat = Xin[n * XDIM + PDIM + lane];
  float outv = feat + acc;
  Xout[n * XDIM + PDIM + lane] = outv;
  if (writeXb) Xb[n * 64 + lane] = f2bf(outv);
  if (lane < PDIM)
    Xout[n * XDIM + lane] = Xin[n * XDIM + lane] + mhs[w][lane];
}

extern "C" void kernel_launch(void* const* d_in, const int* in_sizes, int n_in,
                              void* d_out, int out_size, void* d_ws, size_t ws_size,
                              hipStream_t stream) {
  const float* x      = (const float*)d_in[0];
  const int*   ei     = (const int*)d_in[1];
  const float* eW1    = (const float*)d_in[2];
  const float* eb1    = (const float*)d_in[3];
  const float* eW2    = (const float*)d_in[4];
  const float* eb2    = (const float*)d_in[5];
  const float* cW1    = (const float*)d_in[6];
  const float* cb1    = (const float*)d_in[7];
  const float* cW2    = (const float*)d_in[8];
  const float* cb2    = (const float*)d_in[9];
  const float* nW1    = (const float*)d_in[10];
  const float* nb1    = (const float*)d_in[11];
  const float* nW2    = (const float*)d_in[12];
  const float* nb2    = (const float*)d_in[13];
  const float* cscale = (const float*)d_in[14];

  float* ws     = (float*)d_ws;
  float* X1     = ws;                                   // N*67 f32
  float* mh4    = X1 + N_NODES * XDIM;                  // E*4 f32
  int*   csr    = (int*)(mh4 + (size_t)N_EDGES * 4);    // N+4
  int*   cursor = csr + N_NODES + 4;                    // N
  int*   cnt    = cursor + N_NODES;                     // N
  int*   srcS   = cnt + N_NODES;                        // E
  int*   dstS   = srcS + N_EDGES;                       // E
  unsigned short* w1t  = (unsigned short*)(dstS + N_EDGES);
  unsigned short* w2t  = w1t + NLAYERS * H1T * W1T_K;
  unsigned short* cw1t = w2t + NLAYERS * MDIM * H1T;
  float* b1p = (float*)(cw1t + NLAYERS * CH * MDIM);
  float* wrp = b1p + NLAYERS * H1T;
  unsigned short* Xb = (unsigned short*)(wrp + NLAYERS * H1T);  // N*64 bf16
  unsigned short* ms = Xb + (size_t)N_NODES * 64;               // E*32 bf16

  hipMemsetAsync(cnt, 0, N_NODES * sizeof(int), stream);
  count_kernel<<<(N_EDGES + 255) / 256, 256, 0, stream>>>(ei, cnt);
  scan_kernel<<<1, 1024, 0, stream>>>(cnt, csr, cursor);
  rank_kernel<<<(N_EDGES + 255) / 256, 256, 0, stream>>>(ei, cursor, srcS, dstS);
  {
    const int total = NLAYERS * (H1T * W1T_K + MDIM * H1T + CH * MDIM + 2 * H1T);
    prep_weights<<<(total + 255) / 256, 256, 0, stream>>>(eW1, eW2, cW1, eb1,
                                                          w1t, w2t, cw1t, b1p, wrp);
  }
  convert_x<<<(N_NODES * 8 + 255) / 256, 256, 0, stream>>>(x, Xb);

  for (int l = 0; l < NLAYERS; ++l) {
    const float* Xin = (l == 0) ? x : X1;
    float* Xout = (l == 0) ? X1 : (float*)d_out;
    edge_mfma_kernel<<<N_EDGES / 64, 256, 0, stream>>>(
        Xin, Xb, srcS, dstS, w1t, b1p, wrp, w2t, eb2, cw1t, cb1, cW2, cb2, cscale,
        ms, mh4, l);
    gather_node_kernel<<<N_NODES / 4, 256, 0, stream>>>(
        Xin, ms, mh4, csr, nW1, nb1, nW2, nb2, Xout, Xb, (l == 0) ? 1 : 0, l);
  }
}

// Round 10
// 919.178 us; speedup vs baseline: 1.2969x; 1.1487x over previous
//
#include <hip/hip_runtime.h>

#define N_NODES 50000
#define N_EDGES 800000
#define PDIM 3
#define FDIM 64
#define MDIM 32
#define NLAYERS 2
#define EINDIM 129
#define H1 258          // 2*EIN
#define CH 128          // 4*M
#define NH 128          // 2*F
#define XDIM 67         // P+F
#define K1P 136         // einLds k-stride (bf16): 272B -> 2-way b128 (free)
#define H1T 288         // padded h dim (18 tiles of 16)
#define HSTR 168        // hLds col stride (bf16): 336B -> ~2-way (free)
#define W1T_K 136       // w1t k-dim (128 + 8 pad)
#define MLSTR 40        // ml LDS row stride (bf16)

typedef __attribute__((ext_vector_type(8))) short short8;
typedef __attribute__((ext_vector_type(4))) float f32x4;

#define LOG2E 1.4426950408889634f

__device__ __forceinline__ float fsilu(float x) {
  float e = __builtin_amdgcn_exp2f(-x * LOG2E);
  return x * __builtin_amdgcn_rcpf(1.0f + e);
}

__device__ __forceinline__ float ftanh(float x) {
  float xc = fminf(fmaxf(x, -15.0f), 15.0f);
  float E = __builtin_amdgcn_exp2f(2.0f * LOG2E * xc);
  return (E - 1.0f) * __builtin_amdgcn_rcpf(E + 1.0f);
}

__device__ __forceinline__ unsigned short f2bf(float f) {
  union { float f; unsigned u; } v; v.f = f;
  unsigned r = v.u + 0x7FFF + ((v.u >> 16) & 1);  // RNE
  return (unsigned short)(r >> 16);
}

__device__ __forceinline__ float bf2f(unsigned short u) {
  union { unsigned u; float f; } v; v.u = ((unsigned)u) << 16;
  return v.f;
}

__device__ __forceinline__ unsigned cvt_pk(float lo, float hi) {
  unsigned r;
  asm("v_cvt_pk_bf16_f32 %0, %1, %2" : "=v"(r) : "v"(lo), "v"(hi));
  return r;
}

// bijective XCD-chunk swizzle (m204)
__device__ __forceinline__ int xcd_swz(int bid, int nwg) {
  const int nx = 8;
  int q = nwg / nx, r = nwg % nx;
  int xcd = bid % nx, idx = bid / nx;
  return (xcd < r) ? xcd * (q + 1) + idx : r * (q + 1) + (xcd - r) * q + idx;
}

// ---- CSR build ----
__global__ void count_kernel(const int* __restrict__ ei, int* __restrict__ cnt) {
  int e = blockIdx.x * 256 + threadIdx.x;
  if (e < N_EDGES) atomicAdd(&cnt[ei[N_EDGES + e]], 1);
}

__global__ __launch_bounds__(1024)
void scan_kernel(const int* __restrict__ cnt, int* __restrict__ csr, int* __restrict__ cursor) {
  __shared__ int partial[1024];
  const int tid = threadIdx.x;
  const int CHUNK = 49;
  int base = tid * CHUNK;
  int s = 0;
  for (int i = 0; i < CHUNK; ++i) {
    int idx = base + i;
    if (idx < N_NODES) s += cnt[idx];
  }
  partial[tid] = s;
  __syncthreads();
  for (int off = 1; off < 1024; off <<= 1) {
    int v = (tid >= off) ? partial[tid - off] : 0;
    __syncthreads();
    partial[tid] += v;
    __syncthreads();
  }
  int run = partial[tid] - s;
  for (int i = 0; i < CHUNK; ++i) {
    int idx = base + i;
    if (idx < N_NODES) {
      csr[idx] = run;
      cursor[idx] = run;
      run += cnt[idx];
    }
  }
  if (tid == 1023) csr[N_NODES] = run;
}

// sort edges by dst: slot p gets (src, dst)
__global__ void rank_kernel(const int* __restrict__ ei, int* __restrict__ cursor,
                            int* __restrict__ srcS, int* __restrict__ dstS) {
  int e = blockIdx.x * 256 + threadIdx.x;
  if (e < N_EDGES) {
    int s = ei[e];
    int d = ei[N_EDGES + e];
    int p = atomicAdd(&cursor[d], 1);
    srcS[p] = s;
    dstS[p] = d;
  }
}

// ---- weight prep ----
__global__ void prep_weights(const float* __restrict__ eW1, const float* __restrict__ eW2,
                             const float* __restrict__ cW1, const float* __restrict__ eb1,
                             unsigned short* __restrict__ w1t, unsigned short* __restrict__ w2t,
                             unsigned short* __restrict__ cw1t,
                             float* __restrict__ b1p, float* __restrict__ wrp) {
  int idx = blockIdx.x * 256 + threadIdx.x;
  const int n1 = NLAYERS * H1T * W1T_K;
  const int n2 = NLAYERS * MDIM * H1T;
  const int n3 = NLAYERS * CH * MDIM;
  const int n4 = NLAYERS * H1T;
  if (idx < n1) {
    int k = idx % W1T_K;
    int rest = idx / W1T_K;
    int j = rest % H1T;
    int l = rest / H1T;
    float v = (k < 128 && j < H1) ? eW1[(l * EINDIM + k) * H1 + j] : 0.0f;
    w1t[idx] = f2bf(v);
  } else if (idx < n1 + n2) {
    int t = idx - n1;
    int k = t % H1T;
    int rest = t / H1T;
    int n = rest % MDIM;
    int l = rest / MDIM;
    float v = (k < H1) ? eW2[(l * H1 + k) * MDIM + n] : 0.0f;
    w2t[t] = f2bf(v);
  } else if (idx < n1 + n2 + n3) {
    int t = idx - n1 - n2;
    int k = t % MDIM;
    int rest = t / MDIM;
    int n = rest % CH;
    int l = rest / CH;
    cw1t[t] = f2bf(cW1[(l * MDIM + k) * CH + n]);
  } else if (idx < n1 + n2 + n3 + n4) {
    int t = idx - n1 - n2 - n3;
    int j = t % H1T;
    int l = t / H1T;
    b1p[t] = (j < H1) ? eb1[l * H1 + j] : 0.0f;
  } else if (idx < n1 + n2 + n3 + 2 * n4) {
    int t = idx - n1 - n2 - n3 - n4;
    int j = t % H1T;
    int l = t / H1T;
    wrp[t] = (j < H1) ? eW1[((size_t)l * EINDIM + 128) * H1 + j] : 0.0f;
  }
}

// convert X features to bf16 [N][64]
__global__ void convert_x(const float* __restrict__ X, unsigned short* __restrict__ Xb) {
  int idx = blockIdx.x * 256 + threadIdx.x;
  if (idx >= N_NODES * 8) return;
  int n = idx >> 3, c = idx & 7;
  const float* src = X + n * XDIM + PDIM + c * 8;
  short8 v;
  #pragma unroll
  for (int i = 0; i < 8; ++i) v[i] = (short)f2bf(src[i]);
  *(short8*)&Xb[n * 64 + c * 8] = v;
}

// R9 structure with einLds: B-fragments re-read from LDS (no 64-VGPR fragment
// cache -> no scratch spill), (256,3) for pipelining headroom.
__global__ __launch_bounds__(256, 3)
void edge_mfma_kernel(const float* __restrict__ X,
                      const unsigned short* __restrict__ Xb,
                      const int* __restrict__ srcS, const int* __restrict__ dstS,
                      const unsigned short* __restrict__ w1t,
                      const float* __restrict__ b1p, const float* __restrict__ wrp,
                      const unsigned short* __restrict__ w2t, const float* __restrict__ eb2,
                      const unsigned short* __restrict__ cw1t, const float* __restrict__ cb1,
                      const float* __restrict__ cW2, const float* __restrict__ cb2,
                      const float* __restrict__ cscale,
                      unsigned short* __restrict__ ms, float* __restrict__ mh4,
                      int layer)
{
  __shared__ unsigned short einLds[64 * K1P];  // 17408 B
  __shared__ unsigned short hLds[64 * HSTR];   // 21504 B
  __shared__ unsigned short ml[64 * MLSTR];    //  5120 B
  __shared__ float distLds[64];
  __shared__ float rel3[64 * 3];
  __shared__ int sdS[64], sdD[64];

  const int tid = threadIdx.x;
  const int lane = tid & 63;
  const int wid = tid >> 6;
  const int ln15 = lane & 15;
  const int kg = lane >> 4;
  const int e0 = xcd_swz(blockIdx.x, gridDim.x) * 64;
  const int erow = wid * 16 + ln15;   // own edge row for phases C/D

  if (tid < 64) {
    int s = srcS[e0 + tid];
    int d = dstS[e0 + tid];
    sdS[tid] = s; sdD[tid] = d;
    float rx = X[s * XDIM + 0] - X[d * XDIM + 0];
    float ry = X[s * XDIM + 1] - X[d * XDIM + 1];
    float rz = X[s * XDIM + 2] - X[d * XDIM + 2];
    rel3[tid * 3 + 0] = rx;
    rel3[tid * 3 + 1] = ry;
    rel3[tid * 3 + 2] = rz;
    distLds[tid] = rx * rx + ry * ry + rz * rz;
  }
  __syncthreads();

  // stage e_in bf16 [64 e][128 k] = [featsB[dst] | featsB[src]], coalesced
  #pragma unroll
  for (int it = 0; it < 4; ++it) {
    int idx = tid + it * 256;
    int e = idx >> 4, c = idx & 15;
    int node = (c < 8) ? sdD[e] : sdS[e];
    short8 v = *(const short8*)&Xb[node * 64 + (c & 7) * 8];
    *(short8*)&einLds[e * K1P + c * 8] = v;
  }
  __syncthreads();

  float distE[4];
  #pragma unroll
  for (int et = 0; et < 4; ++et) distE[et] = distLds[et * 16 + ln15];

  const unsigned short* W1T = w1t + layer * H1T * W1T_K;
  const float* B1P = b1p + layer * H1T;
  const float* WRP = wrp + layer * H1T;
  const unsigned short* W2T = w2t + layer * MDIM * H1T;
  const float* B2 = eb2 + layer * MDIM;

  float b20 = B2[ln15], b21 = B2[16 + ln15];
  f32x4 mac0 = {b20, b20, b20, b20};
  f32x4 mac1 = {b21, b21, b21, b21};

  #pragma unroll 1
  for (int half = 0; half < 2; ++half) {
    const int jt0 = half ? 10 : 0;
    const int njt = half ? 8 : 10;
    // ---- phase B: waves split j-tiles; A from global (pipelined), B from LDS ----
    for (int jl = wid; jl < njt; jl += 4) {
      const int jt = jt0 + jl;
      f32x4 b4 = *(const f32x4*)&B1P[jt * 16 + kg * 4];
      f32x4 w4 = *(const f32x4*)&WRP[jt * 16 + kg * 4];
      short8 a[4];
      #pragma unroll
      for (int ks = 0; ks < 4; ++ks)
        a[ks] = *(const short8*)&W1T[(jt * 16 + ln15) * W1T_K + ks * 32 + kg * 8];
      #pragma unroll
      for (int et = 0; et < 4; ++et) {
        f32x4 acc;
        #pragma unroll
        for (int r = 0; r < 4; ++r) acc[r] = fmaf(distE[et], w4[r], b4[r]);
        #pragma unroll
        for (int ks = 0; ks < 4; ++ks) {
          short8 b = *(const short8*)&einLds[(et * 16 + ln15) * K1P + ks * 32 + kg * 8];
          acc = __builtin_amdgcn_mfma_f32_16x16x32_bf16(a[ks], b, acc, 0, 0, 0);
        }
        // C-layout: col = ln15 = edge (tile et), rows j = jt*16 + kg*4 + r
        uint2 uu;
        uu.x = cvt_pk(fsilu(acc[0]), fsilu(acc[1]));
        uu.y = cvt_pk(fsilu(acc[2]), fsilu(acc[3]));
        *(uint2*)&hLds[(et * 16 + ln15) * HSTR + jl * 16 + kg * 4] = uu;
      }
    }
    __syncthreads();

    // ---- phase C partial: own 16 edges, this half's k range ----
    const int nks = half ? 4 : 5;
    #pragma unroll
    for (int ksl = 0; ksl < nks; ++ksl) {
      const int kglob = half * 160 + ksl * 32;
      short8 ah = *(const short8*)&hLds[erow * HSTR + ksl * 32 + kg * 8];
      short8 w0 = *(const short8*)&W2T[ln15 * H1T + kglob + kg * 8];
      short8 w1 = *(const short8*)&W2T[(16 + ln15) * H1T + kglob + kg * 8];
      mac0 = __builtin_amdgcn_mfma_f32_16x16x32_bf16(ah, w0, mac0, 0, 0, 0);
      mac1 = __builtin_amdgcn_mfma_f32_16x16x32_bf16(ah, w1, mac1, 0, 0, 0);
    }
    if (half == 0) __syncthreads();  // protect hLds before overwrite
  }

  // m -> ml (wave-local LDS transpose)
  #pragma unroll
  for (int r = 0; r < 4; ++r) {
    int e = wid * 16 + kg * 4 + r;
    ml[e * MLSTR + ln15] = f2bf(fsilu(mac0[r]));
    ml[e * MLSTR + 16 + ln15] = f2bf(fsilu(mac1[r]));
  }

  // ---- phase D: cw = tanh(sum_n silu(m @ cW1 + cb1)*cW2 + cb2) ----
  const unsigned short* CW1T = cw1t + layer * CH * MDIM;
  const float* CB1 = cb1 + layer * CH;
  const float* CW2v = cW2 + layer * CH;
  short8 am = *(const short8*)&ml[erow * MLSTR + kg * 8];
  float psum[4] = {0.f, 0.f, 0.f, 0.f};
  #pragma unroll
  for (int nt = 0; nt < 8; ++nt) {
    float cb = CB1[nt * 16 + ln15];
    f32x4 cacc = {cb, cb, cb, cb};
    short8 bc = *(const short8*)&CW1T[(nt * 16 + ln15) * MDIM + kg * 8];
    cacc = __builtin_amdgcn_mfma_f32_16x16x32_bf16(am, bc, cacc, 0, 0, 0);
    float w2v = CW2v[nt * 16 + ln15];
    #pragma unroll
    for (int r = 0; r < 4; ++r) psum[r] += fsilu(cacc[r]) * w2v;
  }
  #pragma unroll
  for (int off = 1; off < 16; off <<= 1) {
    #pragma unroll
    for (int r = 0; r < 4; ++r) psum[r] += __shfl_xor(psum[r], off, 64);
  }
  float cwv = 0.0f;
  #pragma unroll
  for (int r = 0; r < 4; ++r) {
    float t = __shfl(psum[r], ((lane & 15) >> 2) * 16, 64);
    if ((lane & 3) == r) cwv = t;
  }

  // coalesced linear m_ij write
  {
    int e_loc = lane >> 2, seg = lane & 3;
    short8 v = *(const short8*)&ml[(wid * 16 + e_loc) * MLSTR + seg * 8];
    *(short8*)&ms[(size_t)(e0 + wid * 16 + e_loc) * MDIM + seg * 8] = v;
  }
  if (lane < 16) {
    int eg = e0 + erow;
    float cw = ftanh(cwv + cb2[layer]);
    float fac = cw * cscale[layer] / fmaxf(sqrtf(distLds[erow]), 1e-8f);
    *(float4*)&mh4[(size_t)eg * 4] =
        make_float4(fac * rel3[erow * 3 + 0], fac * rel3[erow * 3 + 1],
                    fac * rel3[erow * 3 + 2], 0.0f);
  }
}

__global__ __launch_bounds__(256)
void gather_node_kernel(const float* __restrict__ Xin,
                        const unsigned short* __restrict__ ms,
                        const float* __restrict__ mh4,
                        const int* __restrict__ csr,
                        const float* __restrict__ nW1, const float* __restrict__ nb1,
                        const float* __restrict__ nW2, const float* __restrict__ nb2,
                        float* __restrict__ Xout, unsigned short* __restrict__ Xb,
                        int writeXb, int layer)
{
  __shared__ float nin[4][97];
  __shared__ float hn[4][NH + 1];
  __shared__ float mhs[4][3];
  const int tid = threadIdx.x;
  const int w = tid >> 6;
  const int lane = tid & 63;
  const int n = xcd_swz(blockIdx.x, gridDim.x) * 4 + w;

  const int off = csr[n];
  const int end = csr[n + 1];

  // m_i gather: 4 rows/iter, uint loads
  {
    float s0 = 0.0f, s1 = 0.0f;
    for (int r = off + (lane >> 4); r < end; r += 4) {
      unsigned u = *(const unsigned*)&ms[(size_t)r * MDIM + (lane & 15) * 2];
      union { unsigned u; float f; } lo, hi;
      lo.u = u << 16;
      hi.u = u & 0xFFFF0000u;
      s0 += lo.f;
      s1 += hi.f;
    }
    s0 += __shfl_xor(s0, 16, 64);
    s1 += __shfl_xor(s1, 16, 64);
    s0 += __shfl_xor(s0, 32, 64);
    s1 += __shfl_xor(s1, 32, 64);
    if (lane < 16) {
      nin[w][FDIM + lane * 2] = s0;
      nin[w][FDIM + lane * 2 + 1] = s1;
    }
  }
  // mhat_i gather
  {
    const int mc = lane & 3;
    const int mr = lane >> 2;
    float t = 0.0f;
    for (int r = off + mr; r < end; r += 16)
      t += mh4[(size_t)r * 4 + mc];
    t += __shfl_xor(t, 4, 64);
    t += __shfl_xor(t, 8, 64);
    t += __shfl_xor(t, 16, 64);
    t += __shfl_xor(t, 32, 64);
    if (lane < 3) mhs[w][lane] = t;
  }
  nin[w][lane] = Xin[n * XDIM + PDIM + lane];
  __syncthreads();

  const float* W1 = nW1 + layer * (FDIM + MDIM) * NH;
  const float* B1 = nb1 + layer * NH;
  float a0 = B1[lane];
  float a1 = B1[lane + 64];
  #pragma unroll 4
  for (int k = 0; k < FDIM + MDIM; ++k) {
    float v = nin[w][k];
    a0 = fmaf(v, W1[k * NH + lane], a0);
    a1 = fmaf(v, W1[k * NH + lane + 64], a1);
  }
  hn[w][lane] = fsilu(a0);
  hn[w][lane + 64] = fsilu(a1);
  __syncthreads();

  const float* W2 = nW2 + layer * NH * FDIM;
  float acc = nb2[layer * FDIM + lane];
  #pragma unroll 4
  for (int k = 0; k < NH; ++k)
    acc = fmaf(hn[w][k], W2[k * FDIM + lane], acc);

  float feat = Xin[n * XDIM + PDIM + lane];
  float outv = feat + acc;
  Xout[n * XDIM + PDIM + lane] = outv;
  if (writeXb) Xb[n * 64 + lane] = f2bf(outv);
  if (lane < PDIM)
    Xout[n * XDIM + lane] = Xin[n * XDIM + lane] + mhs[w][lane];
}

extern "C" void kernel_launch(void* const* d_in, const int* in_sizes, int n_in,
                              void* d_out, int out_size, void* d_ws, size_t ws_size,
                              hipStream_t stream) {
  const float* x      = (const float*)d_in[0];
  const int*   ei     = (const int*)d_in[1];
  const float* eW1    = (const float*)d_in[2];
  const float* eb1    = (const float*)d_in[3];
  const float* eW2    = (const float*)d_in[4];
  const float* eb2    = (const float*)d_in[5];
  const float* cW1    = (const float*)d_in[6];
  const float* cb1    = (const float*)d_in[7];
  const float* cW2    = (const float*)d_in[8];
  const float* cb2    = (const float*)d_in[9];
  const float* nW1    = (const float*)d_in[10];
  const float* nb1    = (const float*)d_in[11];
  const float* nW2    = (const float*)d_in[12];
  const float* nb2    = (const float*)d_in[13];
  const float* cscale = (const float*)d_in[14];

  float* ws     = (float*)d_ws;
  float* X1     = ws;                                   // N*67 f32
  float* mh4    = X1 + N_NODES * XDIM;                  // E*4 f32
  int*   csr    = (int*)(mh4 + (size_t)N_EDGES * 4);    // N+4
  int*   cursor = csr + N_NODES + 4;                    // N
  int*   cnt    = cursor + N_NODES;                     // N
  int*   srcS   = cnt + N_NODES;                        // E
  int*   dstS   = srcS + N_EDGES;                       // E
  unsigned short* w1t  = (unsigned short*)(dstS + N_EDGES);
  unsigned short* w2t  = w1t + NLAYERS * H1T * W1T_K;
  unsigned short* cw1t = w2t + NLAYERS * MDIM * H1T;
  float* b1p = (float*)(cw1t + NLAYERS * CH * MDIM);
  float* wrp = b1p + NLAYERS * H1T;
  unsigned short* Xb = (unsigned short*)(wrp + NLAYERS * H1T);  // N*64 bf16
  unsigned short* ms = Xb + (size_t)N_NODES * 64;               // E*32 bf16

  hipMemsetAsync(cnt, 0, N_NODES * sizeof(int), stream);
  count_kernel<<<(N_EDGES + 255) / 256, 256, 0, stream>>>(ei, cnt);
  scan_kernel<<<1, 1024, 0, stream>>>(cnt, csr, cursor);
  rank_kernel<<<(N_EDGES + 255) / 256, 256, 0, stream>>>(ei, cursor, srcS, dstS);
  {
    const int total = NLAYERS * (H1T * W1T_K + MDIM * H1T + CH * MDIM + 2 * H1T);
    prep_weights<<<(total + 255) / 256, 256, 0, stream>>>(eW1, eW2, cW1, eb1,
                                                          w1t, w2t, cw1t, b1p, wrp);
  }
  convert_x<<<(N_NODES * 8 + 255) / 256, 256, 0, stream>>>(x, Xb);

  for (int l = 0; l < NLAYERS; ++l) {
    const float* Xin = (l == 0) ? x : X1;
    float* Xout = (l == 0) ? X1 : (float*)d_out;
    edge_mfma_kernel<<<N_EDGES / 64, 256, 0, stream>>>(
        Xin, Xb, srcS, dstS, w1t, b1p, wrp, w2t, eb2, cw1t, cb1, cW2, cb2, cscale,
        ms, mh4, l);
    gather_node_kernel<<<N_NODES / 4, 256, 0, stream>>>(
        Xin, ms, mh4, csr, nW1, nb1, nW2, nb2, Xout, Xb, (l == 0) ? 1 : 0, l);
  }
}

// Round 11
// 734.852 us; speedup vs baseline: 1.6222x; 1.2508x over previous
//
#include <hip/hip_runtime.h>

#define N_NODES 50000
#define N_EDGES 800000
#define PDIM 3
#define FDIM 64
#define MDIM 32
#define NLAYERS 2
#define EINDIM 129
#define H1 258          // 2*EIN
#define CH 128          // 4*M
#define NH 128          // 2*F
#define XDIM 67         // P+F
#define K1P 136         // einLds k-stride (bf16)
#define H1T 288         // padded h dim (18 tiles of 16)
#define HSTR 168        // hLds col stride (bf16)
#define W1T_K 136       // w1t k-dim (128 + 8 pad)
#define MLSTR 40        // ml LDS row stride (bf16)
#define NINS 104        // node n_in LDS k-stride (96 + 8 pad)
#define NH1S 136        // node h1 LDS j-stride (128 + 8 pad)
#define NW2K 128        // nw2t k-dim

typedef __attribute__((ext_vector_type(8))) short short8;
typedef __attribute__((ext_vector_type(4))) float f32x4;

#define LOG2E 1.4426950408889634f

__device__ __forceinline__ float fsilu(float x) {
  float e = __builtin_amdgcn_exp2f(-x * LOG2E);
  return x * __builtin_amdgcn_rcpf(1.0f + e);
}

__device__ __forceinline__ float ftanh(float x) {
  float xc = fminf(fmaxf(x, -15.0f), 15.0f);
  float E = __builtin_amdgcn_exp2f(2.0f * LOG2E * xc);
  return (E - 1.0f) * __builtin_amdgcn_rcpf(E + 1.0f);
}

__device__ __forceinline__ unsigned short f2bf(float f) {
  union { float f; unsigned u; } v; v.f = f;
  unsigned r = v.u + 0x7FFF + ((v.u >> 16) & 1);  // RNE
  return (unsigned short)(r >> 16);
}

__device__ __forceinline__ unsigned cvt_pk(float lo, float hi) {
  unsigned r;
  asm("v_cvt_pk_bf16_f32 %0, %1, %2" : "=v"(r) : "v"(lo), "v"(hi));
  return r;
}

// bijective XCD-chunk swizzle (m204)
__device__ __forceinline__ int xcd_swz(int bid, int nwg) {
  const int nx = 8;
  int q = nwg / nx, r = nwg % nx;
  int xcd = bid % nx, idx = bid / nx;
  return (xcd < r) ? xcd * (q + 1) + idx : r * (q + 1) + (xcd - r) * q + idx;
}

// ---- CSR build ----
__global__ void count_kernel(const int* __restrict__ ei, int* __restrict__ cnt) {
  int e = blockIdx.x * 256 + threadIdx.x;
  if (e < N_EDGES) atomicAdd(&cnt[ei[N_EDGES + e]], 1);
}

__global__ __launch_bounds__(1024)
void scan_kernel(const int* __restrict__ cnt, int* __restrict__ csr, int* __restrict__ cursor) {
  __shared__ int partial[1024];
  const int tid = threadIdx.x;
  const int CHUNK = 49;
  int base = tid * CHUNK;
  int s = 0;
  for (int i = 0; i < CHUNK; ++i) {
    int idx = base + i;
    if (idx < N_NODES) s += cnt[idx];
  }
  partial[tid] = s;
  __syncthreads();
  for (int off = 1; off < 1024; off <<= 1) {
    int v = (tid >= off) ? partial[tid - off] : 0;
    __syncthreads();
    partial[tid] += v;
    __syncthreads();
  }
  int run = partial[tid] - s;
  for (int i = 0; i < CHUNK; ++i) {
    int idx = base + i;
    if (idx < N_NODES) {
      csr[idx] = run;
      cursor[idx] = run;
      run += cnt[idx];
    }
  }
  if (tid == 1023) csr[N_NODES] = run;
}

// sort edges by dst: slot p gets (src, dst)
__global__ void rank_kernel(const int* __restrict__ ei, int* __restrict__ cursor,
                            int* __restrict__ srcS, int* __restrict__ dstS) {
  int e = blockIdx.x * 256 + threadIdx.x;
  if (e < N_EDGES) {
    int s = ei[e];
    int d = ei[N_EDGES + e];
    int p = atomicAdd(&cursor[d], 1);
    srcS[p] = s;
    dstS[p] = d;
  }
}

// ---- weight prep ----
__global__ void prep_weights(const float* __restrict__ eW1, const float* __restrict__ eW2,
                             const float* __restrict__ cW1, const float* __restrict__ eb1,
                             const float* __restrict__ nW1, const float* __restrict__ nW2,
                             unsigned short* __restrict__ w1t, unsigned short* __restrict__ w2t,
                             unsigned short* __restrict__ cw1t,
                             unsigned short* __restrict__ nw1t, unsigned short* __restrict__ nw2t,
                             float* __restrict__ b1p, float* __restrict__ wrp) {
  int idx = blockIdx.x * 256 + threadIdx.x;
  const int n1 = NLAYERS * H1T * W1T_K;
  const int n2 = NLAYERS * MDIM * H1T;
  const int n3 = NLAYERS * CH * MDIM;
  const int n4 = NLAYERS * H1T;
  const int n5 = NLAYERS * NH * NINS;
  const int n6 = NLAYERS * FDIM * NW2K;
  if (idx < n1) {
    int k = idx % W1T_K;
    int rest = idx / W1T_K;
    int j = rest % H1T;
    int l = rest / H1T;
    float v = (k < 128 && j < H1) ? eW1[(l * EINDIM + k) * H1 + j] : 0.0f;
    w1t[idx] = f2bf(v);
  } else if (idx < n1 + n2) {
    int t = idx - n1;
    int k = t % H1T;
    int rest = t / H1T;
    int n = rest % MDIM;
    int l = rest / MDIM;
    float v = (k < H1) ? eW2[(l * H1 + k) * MDIM + n] : 0.0f;
    w2t[t] = f2bf(v);
  } else if (idx < n1 + n2 + n3) {
    int t = idx - n1 - n2;
    int k = t % MDIM;
    int rest = t / MDIM;
    int n = rest % CH;
    int l = rest / CH;
    cw1t[t] = f2bf(cW1[(l * MDIM + k) * CH + n]);
  } else if (idx < n1 + n2 + n3 + n4) {
    int t = idx - n1 - n2 - n3;
    int j = t % H1T;
    int l = t / H1T;
    b1p[t] = (j < H1) ? eb1[l * H1 + j] : 0.0f;
  } else if (idx < n1 + n2 + n3 + 2 * n4) {
    int t = idx - n1 - n2 - n3 - n4;
    int j = t % H1T;
    int l = t / H1T;
    wrp[t] = (j < H1) ? eW1[((size_t)l * EINDIM + 128) * H1 + j] : 0.0f;
  } else if (idx < n1 + n2 + n3 + 2 * n4 + n5) {
    int t = idx - n1 - n2 - n3 - 2 * n4;
    int k = t % NINS;
    int rest = t / NINS;
    int j = rest % NH;
    int l = rest / NH;
    float v = (k < FDIM + MDIM) ? nW1[(l * (FDIM + MDIM) + k) * NH + j] : 0.0f;
    nw1t[t] = f2bf(v);
  } else if (idx < n1 + n2 + n3 + 2 * n4 + n5 + n6) {
    int t = idx - n1 - n2 - n3 - 2 * n4 - n5;
    int k = t % NW2K;
    int rest = t / NW2K;
    int j = rest % FDIM;
    int l = rest / FDIM;
    nw2t[t] = f2bf(nW2[(l * NH + k) * FDIM + j]);
  }
}

// convert X features to bf16 [N][64]
__global__ void convert_x(const float* __restrict__ X, unsigned short* __restrict__ Xb) {
  int idx = blockIdx.x * 256 + threadIdx.x;
  if (idx >= N_NODES * 8) return;
  int n = idx >> 3, c = idx & 7;
  const float* src = X + n * XDIM + PDIM + c * 8;
  short8 v;
  #pragma unroll
  for (int i = 0; i < 8; ++i) v[i] = (short)f2bf(src[i]);
  *(short8*)&Xb[n * 64 + c * 8] = v;
}

// ---- edge kernel (frozen from R10: best known, 241us) ----
__global__ __launch_bounds__(256, 3)
void edge_mfma_kernel(const float* __restrict__ X,
                      const unsigned short* __restrict__ Xb,
                      const int* __restrict__ srcS, const int* __restrict__ dstS,
                      const unsigned short* __restrict__ w1t,
                      const float* __restrict__ b1p, const float* __restrict__ wrp,
                      const unsigned short* __restrict__ w2t, const float* __restrict__ eb2,
                      const unsigned short* __restrict__ cw1t, const float* __restrict__ cb1,
                      const float* __restrict__ cW2, const float* __restrict__ cb2,
                      const float* __restrict__ cscale,
                      unsigned short* __restrict__ ms, float* __restrict__ mh4,
                      int layer)
{
  __shared__ unsigned short einLds[64 * K1P];
  __shared__ unsigned short hLds[64 * HSTR];
  __shared__ unsigned short ml[64 * MLSTR];
  __shared__ float distLds[64];
  __shared__ float rel3[64 * 3];
  __shared__ int sdS[64], sdD[64];

  const int tid = threadIdx.x;
  const int lane = tid & 63;
  const int wid = tid >> 6;
  const int ln15 = lane & 15;
  const int kg = lane >> 4;
  const int e0 = xcd_swz(blockIdx.x, gridDim.x) * 64;
  const int erow = wid * 16 + ln15;

  if (tid < 64) {
    int s = srcS[e0 + tid];
    int d = dstS[e0 + tid];
    sdS[tid] = s; sdD[tid] = d;
    float rx = X[s * XDIM + 0] - X[d * XDIM + 0];
    float ry = X[s * XDIM + 1] - X[d * XDIM + 1];
    float rz = X[s * XDIM + 2] - X[d * XDIM + 2];
    rel3[tid * 3 + 0] = rx;
    rel3[tid * 3 + 1] = ry;
    rel3[tid * 3 + 2] = rz;
    distLds[tid] = rx * rx + ry * ry + rz * rz;
  }
  __syncthreads();

  #pragma unroll
  for (int it = 0; it < 4; ++it) {
    int idx = tid + it * 256;
    int e = idx >> 4, c = idx & 15;
    int node = (c < 8) ? sdD[e] : sdS[e];
    short8 v = *(const short8*)&Xb[node * 64 + (c & 7) * 8];
    *(short8*)&einLds[e * K1P + c * 8] = v;
  }
  __syncthreads();

  float distE[4];
  #pragma unroll
  for (int et = 0; et < 4; ++et) distE[et] = distLds[et * 16 + ln15];

  const unsigned short* W1T = w1t + layer * H1T * W1T_K;
  const float* B1P = b1p + layer * H1T;
  const float* WRP = wrp + layer * H1T;
  const unsigned short* W2T = w2t + layer * MDIM * H1T;
  const float* B2 = eb2 + layer * MDIM;

  float b20 = B2[ln15], b21 = B2[16 + ln15];
  f32x4 mac0 = {b20, b20, b20, b20};
  f32x4 mac1 = {b21, b21, b21, b21};

  #pragma unroll 1
  for (int half = 0; half < 2; ++half) {
    const int jt0 = half ? 10 : 0;
    const int njt = half ? 8 : 10;
    for (int jl = wid; jl < njt; jl += 4) {
      const int jt = jt0 + jl;
      f32x4 b4 = *(const f32x4*)&B1P[jt * 16 + kg * 4];
      f32x4 w4 = *(const f32x4*)&WRP[jt * 16 + kg * 4];
      short8 a[4];
      #pragma unroll
      for (int ks = 0; ks < 4; ++ks)
        a[ks] = *(const short8*)&W1T[(jt * 16 + ln15) * W1T_K + ks * 32 + kg * 8];
      #pragma unroll
      for (int et = 0; et < 4; ++et) {
        f32x4 acc;
        #pragma unroll
        for (int r = 0; r < 4; ++r) acc[r] = fmaf(distE[et], w4[r], b4[r]);
        #pragma unroll
        for (int ks = 0; ks < 4; ++ks) {
          short8 b = *(const short8*)&einLds[(et * 16 + ln15) * K1P + ks * 32 + kg * 8];
          acc = __builtin_amdgcn_mfma_f32_16x16x32_bf16(a[ks], b, acc, 0, 0, 0);
        }
        uint2 uu;
        uu.x = cvt_pk(fsilu(acc[0]), fsilu(acc[1]));
        uu.y = cvt_pk(fsilu(acc[2]), fsilu(acc[3]));
        *(uint2*)&hLds[(et * 16 + ln15) * HSTR + jl * 16 + kg * 4] = uu;
      }
    }
    __syncthreads();

    const int nks = half ? 4 : 5;
    #pragma unroll
    for (int ksl = 0; ksl < nks; ++ksl) {
      const int kglob = half * 160 + ksl * 32;
      short8 ah = *(const short8*)&hLds[erow * HSTR + ksl * 32 + kg * 8];
      short8 w0 = *(const short8*)&W2T[ln15 * H1T + kglob + kg * 8];
      short8 w1 = *(const short8*)&W2T[(16 + ln15) * H1T + kglob + kg * 8];
      mac0 = __builtin_amdgcn_mfma_f32_16x16x32_bf16(ah, w0, mac0, 0, 0, 0);
      mac1 = __builtin_amdgcn_mfma_f32_16x16x32_bf16(ah, w1, mac1, 0, 0, 0);
    }
    if (half == 0) __syncthreads();
  }

  #pragma unroll
  for (int r = 0; r < 4; ++r) {
    int e = wid * 16 + kg * 4 + r;
    ml[e * MLSTR + ln15] = f2bf(fsilu(mac0[r]));
    ml[e * MLSTR + 16 + ln15] = f2bf(fsilu(mac1[r]));
  }

  const unsigned short* CW1T = cw1t + layer * CH * MDIM;
  const float* CB1 = cb1 + layer * CH;
  const float* CW2v = cW2 + layer * CH;
  short8 am = *(const short8*)&ml[erow * MLSTR + kg * 8];
  float psum[4] = {0.f, 0.f, 0.f, 0.f};
  #pragma unroll
  for (int nt = 0; nt < 8; ++nt) {
    float cb = CB1[nt * 16 + ln15];
    f32x4 cacc = {cb, cb, cb, cb};
    short8 bc = *(const short8*)&CW1T[(nt * 16 + ln15) * MDIM + kg * 8];
    cacc = __builtin_amdgcn_mfma_f32_16x16x32_bf16(am, bc, cacc, 0, 0, 0);
    float w2v = CW2v[nt * 16 + ln15];
    #pragma unroll
    for (int r = 0; r < 4; ++r) psum[r] += fsilu(cacc[r]) * w2v;
  }
  #pragma unroll
  for (int off = 1; off < 16; off <<= 1) {
    #pragma unroll
    for (int r = 0; r < 4; ++r) psum[r] += __shfl_xor(psum[r], off, 64);
  }
  float cwv = 0.0f;
  #pragma unroll
  for (int r = 0; r < 4; ++r) {
    float t = __shfl(psum[r], ((lane & 15) >> 2) * 16, 64);
    if ((lane & 3) == r) cwv = t;
  }

  {
    int e_loc = lane >> 2, seg = lane & 3;
    short8 v = *(const short8*)&ml[(wid * 16 + e_loc) * MLSTR + seg * 8];
    *(short8*)&ms[(size_t)(e0 + wid * 16 + e_loc) * MDIM + seg * 8] = v;
  }
  if (lane < 16) {
    int eg = e0 + erow;
    float cw = ftanh(cwv + cb2[layer]);
    float fac = cw * cscale[layer] / fmaxf(sqrtf(distLds[erow]), 1e-8f);
    *(float4*)&mh4[(size_t)eg * 4] =
        make_float4(fac * rel3[erow * 3 + 0], fac * rel3[erow * 3 + 1],
                    fac * rel3[erow * 3 + 2], 0.0f);
  }
}

// ---- MFMA node kernel: block = 64 nodes, 4 waves, j-split like edge phase B ----
__global__ __launch_bounds__(256, 3)
void node_mfma_kernel(const float* __restrict__ Xin,
                      const unsigned short* __restrict__ XbIn,
                      const unsigned short* __restrict__ ms,
                      const float* __restrict__ mh4,
                      const int* __restrict__ csr,
                      const unsigned short* __restrict__ nw1t, const float* __restrict__ nb1,
                      const unsigned short* __restrict__ nw2t, const float* __restrict__ nb2,
                      float* __restrict__ Xout, unsigned short* __restrict__ XbOut,
                      int writeXb, int layer)
{
  __shared__ unsigned short ninLds[64 * NINS];  // 13312 B: [node][k] k=0..95
  __shared__ unsigned short h1Lds[64 * NH1S];   // 17408 B: [node][j] j=0..127
  __shared__ float outLds[64 * 68];             // 17408 B
  __shared__ float mhsLds[64][3];
  __shared__ int csrLds[65];

  const int tid = threadIdx.x;
  const int lane = tid & 63;
  const int wid = tid >> 6;
  const int ln15 = lane & 15;
  const int kg = lane >> 4;
  const int n0 = xcd_swz(blockIdx.x, gridDim.x) * 64;

  if (tid < 65) {
    int nn = n0 + tid;
    csrLds[tid] = (nn <= N_NODES) ? csr[nn] : 0;
  }
  // stage feats bf16 (cols 0..63)
  #pragma unroll
  for (int it = 0; it < 2; ++it) {
    int idx = tid + it * 256;       // 0..511 = 64 nodes x 8 chunks
    int nl = idx >> 3, c = idx & 7;
    int n = n0 + nl;
    uint4 v = make_uint4(0, 0, 0, 0);
    if (n < N_NODES) v = *(const uint4*)&XbIn[n * 64 + c * 8];
    *(uint4*)&ninLds[nl * NINS + c * 8] = v;
  }
  __syncthreads();

  // gather m_i (cols 64..95) + mhat; 4 threads per node
  {
    const int nl = tid >> 2, sub = tid & 3;
    const int n = n0 + nl;
    int off = csrLds[nl], end = csrLds[nl + 1];
    if (n >= N_NODES) { off = 0; end = 0; }
    float s0 = 0, s1 = 0, s2 = 0, s3 = 0, s4 = 0, s5 = 0, s6 = 0, s7 = 0;
    for (int r = off; r < end; ++r) {
      uint4 q = *(const uint4*)&ms[(size_t)r * MDIM + sub * 8];
      union { unsigned u; float f; } t;
      t.u = q.x << 16;         s0 += t.f;
      t.u = q.x & 0xFFFF0000u; s1 += t.f;
      t.u = q.y << 16;         s2 += t.f;
      t.u = q.y & 0xFFFF0000u; s3 += t.f;
      t.u = q.z << 16;         s4 += t.f;
      t.u = q.z & 0xFFFF0000u; s5 += t.f;
      t.u = q.w << 16;         s6 += t.f;
      t.u = q.w & 0xFFFF0000u; s7 += t.f;
    }
    uint4 mo;
    mo.x = cvt_pk(s0, s1);
    mo.y = cvt_pk(s2, s3);
    mo.z = cvt_pk(s4, s5);
    mo.w = cvt_pk(s6, s7);
    *(uint4*)&ninLds[nl * NINS + FDIM + sub * 8] = mo;

    float mx = 0, my = 0, mz = 0;
    for (int r = off + sub; r < end; r += 4) {
      float4 q = *(const float4*)&mh4[(size_t)r * 4];
      mx += q.x; my += q.y; mz += q.z;
    }
    mx += __shfl_xor(mx, 1, 64); mx += __shfl_xor(mx, 2, 64);
    my += __shfl_xor(my, 1, 64); my += __shfl_xor(my, 2, 64);
    mz += __shfl_xor(mz, 1, 64); mz += __shfl_xor(mz, 2, 64);
    if (sub == 0) {
      mhsLds[nl][0] = mx; mhsLds[nl][1] = my; mhsLds[nl][2] = mz;
    }
  }
  __syncthreads();

  // M1: h1T[128][64] = silu(nW1T . n_inT + nb1), K = 96 = 3x32
  const unsigned short* W1 = nw1t + layer * NH * NINS;
  const float* B1 = nb1 + layer * NH;
  for (int jt = wid; jt < 8; jt += 4) {
    f32x4 b4 = *(const f32x4*)&B1[jt * 16 + kg * 4];
    short8 a[3];
    #pragma unroll
    for (int ks = 0; ks < 3; ++ks)
      a[ks] = *(const short8*)&W1[(jt * 16 + ln15) * NINS + ks * 32 + kg * 8];
    #pragma unroll
    for (int et = 0; et < 4; ++et) {
      f32x4 acc = b4;
      #pragma unroll
      for (int ks = 0; ks < 3; ++ks) {
        short8 b = *(const short8*)&ninLds[(et * 16 + ln15) * NINS + ks * 32 + kg * 8];
        acc = __builtin_amdgcn_mfma_f32_16x16x32_bf16(a[ks], b, acc, 0, 0, 0);
      }
      uint2 uu;
      uu.x = cvt_pk(fsilu(acc[0]), fsilu(acc[1]));
      uu.y = cvt_pk(fsilu(acc[2]), fsilu(acc[3]));
      *(uint2*)&h1Lds[(et * 16 + ln15) * NH1S + jt * 16 + kg * 4] = uu;
    }
  }
  __syncthreads();

  // M2: outT[64][64] = nW2T . h1T + nb2, K = 128 = 4x32
  const unsigned short* W2 = nw2t + layer * FDIM * NW2K;
  const float* B2 = nb2 + layer * FDIM;
  {
    int jt = wid;  // 0..3
    f32x4 b4 = *(const f32x4*)&B2[jt * 16 + kg * 4];
    short8 a[4];
    #pragma unroll
    for (int ks = 0; ks < 4; ++ks)
      a[ks] = *(const short8*)&W2[(jt * 16 + ln15) * NW2K + ks * 32 + kg * 8];
    #pragma unroll
    for (int et = 0; et < 4; ++et) {
      f32x4 acc = b4;
      #pragma unroll
      for (int ks = 0; ks < 4; ++ks) {
        short8 b = *(const short8*)&h1Lds[(et * 16 + ln15) * NH1S + ks * 32 + kg * 8];
        acc = __builtin_amdgcn_mfma_f32_16x16x32_bf16(a[ks], b, acc, 0, 0, 0);
      }
      *(f32x4*)&outLds[(et * 16 + ln15) * 68 + jt * 16 + kg * 4] = acc;
    }
  }
  __syncthreads();

  // epilogue: feats residual + optional Xb, coalesced per node row
  #pragma unroll
  for (int it = 0; it < 16; ++it) {
    int idx = tid + it * 256;       // 0..4095 = 64 nodes x 64 cols
    int nl = idx >> 6, c = idx & 63;
    int n = n0 + nl;
    if (n < N_NODES) {
      float v = Xin[n * XDIM + PDIM + c] + outLds[nl * 68 + c];
      Xout[n * XDIM + PDIM + c] = v;
      if (writeXb) XbOut[n * 64 + c] = f2bf(v);
    }
  }
  if (tid < 64) {
    int n = n0 + tid;
    if (n < N_NODES) {
      Xout[n * XDIM + 0] = Xin[n * XDIM + 0] + mhsLds[tid][0];
      Xout[n * XDIM + 1] = Xin[n * XDIM + 1] + mhsLds[tid][1];
      Xout[n * XDIM + 2] = Xin[n * XDIM + 2] + mhsLds[tid][2];
    }
  }
}

extern "C" void kernel_launch(void* const* d_in, const int* in_sizes, int n_in,
                              void* d_out, int out_size, void* d_ws, size_t ws_size,
                              hipStream_t stream) {
  const float* x      = (const float*)d_in[0];
  const int*   ei     = (const int*)d_in[1];
  const float* eW1    = (const float*)d_in[2];
  const float* eb1    = (const float*)d_in[3];
  const float* eW2    = (const float*)d_in[4];
  const float* eb2    = (const float*)d_in[5];
  const float* cW1    = (const float*)d_in[6];
  const float* cb1    = (const float*)d_in[7];
  const float* cW2    = (const float*)d_in[8];
  const float* cb2    = (const float*)d_in[9];
  const float* nW1    = (const float*)d_in[10];
  const float* nb1    = (const float*)d_in[11];
  const float* nW2    = (const float*)d_in[12];
  const float* nb2    = (const float*)d_in[13];
  const float* cscale = (const float*)d_in[14];

  float* ws     = (float*)d_ws;
  float* X1     = ws;                                   // N*67 f32
  float* mh4    = X1 + N_NODES * XDIM;                  // E*4 f32
  int*   csr    = (int*)(mh4 + (size_t)N_EDGES * 4);    // N+4
  int*   cursor = csr + N_NODES + 4;                    // N
  int*   cnt    = cursor + N_NODES;                     // N
  int*   srcS   = cnt + N_NODES;                        // E
  int*   dstS   = srcS + N_EDGES;                       // E
  unsigned short* w1t  = (unsigned short*)(dstS + N_EDGES);
  unsigned short* w2t  = w1t + NLAYERS * H1T * W1T_K;
  unsigned short* cw1t = w2t + NLAYERS * MDIM * H1T;
  unsigned short* nw1t = cw1t + NLAYERS * CH * MDIM;
  unsigned short* nw2t = nw1t + NLAYERS * NH * NINS;
  float* b1p = (float*)(nw2t + NLAYERS * FDIM * NW2K);
  float* wrp = b1p + NLAYERS * H1T;
  unsigned short* Xb = (unsigned short*)(wrp + NLAYERS * H1T);  // N*64 bf16
  unsigned short* ms = Xb + (size_t)N_NODES * 64;               // E*32 bf16

  hipMemsetAsync(cnt, 0, N_NODES * sizeof(int), stream);
  count_kernel<<<(N_EDGES + 255) / 256, 256, 0, stream>>>(ei, cnt);
  scan_kernel<<<1, 1024, 0, stream>>>(cnt, csr, cursor);
  rank_kernel<<<(N_EDGES + 255) / 256, 256, 0, stream>>>(ei, cursor, srcS, dstS);
  {
    const int total = NLAYERS * (H1T * W1T_K + MDIM * H1T + CH * MDIM + 2 * H1T
                                 + NH * NINS + FDIM * NW2K);
    prep_weights<<<(total + 255) / 256, 256, 0, stream>>>(
        eW1, eW2, cW1, eb1, nW1, nW2, w1t, w2t, cw1t, nw1t, nw2t, b1p, wrp);
  }
  convert_x<<<(N_NODES * 8 + 255) / 256, 256, 0, stream>>>(x, Xb);

  const int nodeBlocks = (N_NODES + 63) / 64;
  for (int l = 0; l < NLAYERS; ++l) {
    const float* Xin = (l == 0) ? x : X1;
    float* Xout = (l == 0) ? X1 : (float*)d_out;
    edge_mfma_kernel<<<N_EDGES / 64, 256, 0, stream>>>(
        Xin, Xb, srcS, dstS, w1t, b1p, wrp, w2t, eb2, cw1t, cb1, cW2, cb2, cscale,
        ms, mh4, l);
    node_mfma_kernel<<<nodeBlocks, 256, 0, stream>>>(
        Xin, Xb, ms, mh4, csr, nw1t, nb1, nw2t, nb2, Xout, Xb, (l == 0) ? 1 : 0, l);
  }
}

// Round 12
// 692.495 us; speedup vs baseline: 1.7214x; 1.0612x over previous
//
#include <hip/hip_runtime.h>

#define N_NODES 50000
#define N_EDGES 800000
#define PDIM 3
#define FDIM 64
#define MDIM 32
#define NLAYERS 2
#define EINDIM 129
#define H1 258          // 2*EIN
#define CH 128          // 4*M
#define NH 128          // 2*F
#define XDIM 67         // P+F
#define H1T 288         // padded h dim (18 tiles of 16)
#define HSTR3 104       // hLds col stride (bf16): 96 cols + 8 pad (208B = 13 quanta, odd)
#define W1T_K 136       // w1t k-dim (128 + 8 pad)
#define MLSTR 40        // ml LDS row stride (bf16)
#define NINS 104        // node n_in LDS k-stride (96 + 8 pad)
#define NH1S 136        // node h1 LDS j-stride (128 + 8 pad)
#define NW2K 128        // nw2t k-dim

typedef __attribute__((ext_vector_type(8))) short short8;
typedef __attribute__((ext_vector_type(4))) float f32x4;

#define LOG2E 1.4426950408889634f

__device__ __forceinline__ float fsilu(float x) {
  float e = __builtin_amdgcn_exp2f(-x * LOG2E);
  return x * __builtin_amdgcn_rcpf(1.0f + e);
}

__device__ __forceinline__ float ftanh(float x) {
  float xc = fminf(fmaxf(x, -15.0f), 15.0f);
  float E = __builtin_amdgcn_exp2f(2.0f * LOG2E * xc);
  return (E - 1.0f) * __builtin_amdgcn_rcpf(E + 1.0f);
}

__device__ __forceinline__ unsigned short f2bf(float f) {
  union { float f; unsigned u; } v; v.f = f;
  unsigned r = v.u + 0x7FFF + ((v.u >> 16) & 1);  // RNE
  return (unsigned short)(r >> 16);
}

__device__ __forceinline__ unsigned cvt_pk(float lo, float hi) {
  unsigned r;
  asm("v_cvt_pk_bf16_f32 %0, %1, %2" : "=v"(r) : "v"(lo), "v"(hi));
  return r;
}

// bijective XCD-chunk swizzle (m204)
__device__ __forceinline__ int xcd_swz(int bid, int nwg) {
  const int nx = 8;
  int q = nwg / nx, r = nwg % nx;
  int xcd = bid % nx, idx = bid / nx;
  return (xcd < r) ? xcd * (q + 1) + idx : r * (q + 1) + (xcd - r) * q + idx;
}

// ---- CSR build ----
__global__ void count_kernel(const int* __restrict__ ei, int* __restrict__ cnt) {
  int e = blockIdx.x * 256 + threadIdx.x;
  if (e < N_EDGES) atomicAdd(&cnt[ei[N_EDGES + e]], 1);
}

__global__ __launch_bounds__(1024)
void scan_kernel(const int* __restrict__ cnt, int* __restrict__ csr, int* __restrict__ cursor) {
  __shared__ int partial[1024];
  const int tid = threadIdx.x;
  const int CHUNK = 49;
  int base = tid * CHUNK;
  int s = 0;
  for (int i = 0; i < CHUNK; ++i) {
    int idx = base + i;
    if (idx < N_NODES) s += cnt[idx];
  }
  partial[tid] = s;
  __syncthreads();
  for (int off = 1; off < 1024; off <<= 1) {
    int v = (tid >= off) ? partial[tid - off] : 0;
    __syncthreads();
    partial[tid] += v;
    __syncthreads();
  }
  int run = partial[tid] - s;
  for (int i = 0; i < CHUNK; ++i) {
    int idx = base + i;
    if (idx < N_NODES) {
      csr[idx] = run;
      cursor[idx] = run;
      run += cnt[idx];
    }
  }
  if (tid == 1023) csr[N_NODES] = run;
}

// sort edges by dst: slot p gets (src, dst)
__global__ void rank_kernel(const int* __restrict__ ei, int* __restrict__ cursor,
                            int* __restrict__ srcS, int* __restrict__ dstS) {
  int e = blockIdx.x * 256 + threadIdx.x;
  if (e < N_EDGES) {
    int s = ei[e];
    int d = ei[N_EDGES + e];
    int p = atomicAdd(&cursor[d], 1);
    srcS[p] = s;
    dstS[p] = d;
  }
}

// ---- weight prep ----
__global__ void prep_weights(const float* __restrict__ eW1, const float* __restrict__ eW2,
                             const float* __restrict__ cW1, const float* __restrict__ eb1,
                             const float* __restrict__ nW1, const float* __restrict__ nW2,
                             unsigned short* __restrict__ w1t, unsigned short* __restrict__ w2t,
                             unsigned short* __restrict__ cw1t,
                             unsigned short* __restrict__ nw1t, unsigned short* __restrict__ nw2t,
                             float* __restrict__ b1p, float* __restrict__ wrp) {
  int idx = blockIdx.x * 256 + threadIdx.x;
  const int n1 = NLAYERS * H1T * W1T_K;
  const int n2 = NLAYERS * MDIM * H1T;
  const int n3 = NLAYERS * CH * MDIM;
  const int n4 = NLAYERS * H1T;
  const int n5 = NLAYERS * NH * NINS;
  const int n6 = NLAYERS * FDIM * NW2K;
  if (idx < n1) {
    int k = idx % W1T_K;
    int rest = idx / W1T_K;
    int j = rest % H1T;
    int l = rest / H1T;
    float v = (k < 128 && j < H1) ? eW1[(l * EINDIM + k) * H1 + j] : 0.0f;
    w1t[idx] = f2bf(v);
  } else if (idx < n1 + n2) {
    int t = idx - n1;
    int k = t % H1T;
    int rest = t / H1T;
    int n = rest % MDIM;
    int l = rest / MDIM;
    float v = (k < H1) ? eW2[(l * H1 + k) * MDIM + n] : 0.0f;
    w2t[t] = f2bf(v);
  } else if (idx < n1 + n2 + n3) {
    int t = idx - n1 - n2;
    int k = t % MDIM;
    int rest = t / MDIM;
    int n = rest % CH;
    int l = rest / CH;
    cw1t[t] = f2bf(cW1[(l * MDIM + k) * CH + n]);
  } else if (idx < n1 + n2 + n3 + n4) {
    int t = idx - n1 - n2 - n3;
    int j = t % H1T;
    int l = t / H1T;
    b1p[t] = (j < H1) ? eb1[l * H1 + j] : 0.0f;
  } else if (idx < n1 + n2 + n3 + 2 * n4) {
    int t = idx - n1 - n2 - n3 - n4;
    int j = t % H1T;
    int l = t / H1T;
    wrp[t] = (j < H1) ? eW1[((size_t)l * EINDIM + 128) * H1 + j] : 0.0f;
  } else if (idx < n1 + n2 + n3 + 2 * n4 + n5) {
    int t = idx - n1 - n2 - n3 - 2 * n4;
    int k = t % NINS;
    int rest = t / NINS;
    int j = rest % NH;
    int l = rest / NH;
    float v = (k < FDIM + MDIM) ? nW1[(l * (FDIM + MDIM) + k) * NH + j] : 0.0f;
    nw1t[t] = f2bf(v);
  } else if (idx < n1 + n2 + n3 + 2 * n4 + n5 + n6) {
    int t = idx - n1 - n2 - n3 - 2 * n4 - n5;
    int k = t % NW2K;
    int rest = t / NW2K;
    int j = rest % FDIM;
    int l = rest / FDIM;
    nw2t[t] = f2bf(nW2[(l * NH + k) * FDIM + j]);
  }
}

// convert X features to bf16 [N][64]
__global__ void convert_x(const float* __restrict__ X, unsigned short* __restrict__ Xb) {
  int idx = blockIdx.x * 256 + threadIdx.x;
  if (idx >= N_NODES * 8) return;
  int n = idx >> 3, c = idx & 7;
  const float* src = X + n * XDIM + PDIM + c * 8;
  short8 v;
  #pragma unroll
  for (int i = 0; i < 8; ++i) v[i] = (short)f2bf(src[i]);
  *(short8*)&Xb[n * 64 + c * 8] = v;
}

// Edge kernel v3: 128 edges/block, 2 edge-tiles per wave, einB in registers
// (32 VGPR, no spill), zero __syncthreads (all LDS wave-partitioned),
// 3-chunk hLds -> 36.9KB LDS -> 4 blocks/CU.
__global__ __launch_bounds__(256, 4)
void edge_mfma_kernel(const float* __restrict__ X,
                      const unsigned short* __restrict__ Xb,
                      const int* __restrict__ srcS, const int* __restrict__ dstS,
                      const unsigned short* __restrict__ w1t,
                      const float* __restrict__ b1p, const float* __restrict__ wrp,
                      const unsigned short* __restrict__ w2t, const float* __restrict__ eb2,
                      const unsigned short* __restrict__ cw1t, const float* __restrict__ cb1,
                      const float* __restrict__ cW2, const float* __restrict__ cb2,
                      const float* __restrict__ cscale,
                      unsigned short* __restrict__ ms, float* __restrict__ mh4,
                      int layer)
{
  __shared__ unsigned short hLds[128 * HSTR3];  // 26624 B, rows wave-partitioned
  __shared__ unsigned short ml[128 * MLSTR];    // 10240 B, rows wave-partitioned

  const int tid = threadIdx.x;
  const int lane = tid & 63;
  const int wid = tid >> 6;
  const int ln15 = lane & 15;
  const int kg = lane >> 4;
  const int e0 = xcd_swz(blockIdx.x, gridDim.x) * 128;
  const int ew0 = e0 + wid * 32;         // this wave's 32 edges

  // per-lane edge data for its two tile-edges (kg groups duplicate: broadcast)
  const int eA = ew0 + ln15;             // et = 0
  const int eB = ew0 + 16 + ln15;        // et = 1
  const int sA = srcS[eA], dA = dstS[eA];
  const int sB = srcS[eB], dB = dstS[eB];
  float rxA = X[sA * XDIM + 0] - X[dA * XDIM + 0];
  float ryA = X[sA * XDIM + 1] - X[dA * XDIM + 1];
  float rzA = X[sA * XDIM + 2] - X[dA * XDIM + 2];
  float rxB = X[sB * XDIM + 0] - X[dB * XDIM + 0];
  float ryB = X[sB * XDIM + 1] - X[dB * XDIM + 1];
  float rzB = X[sB * XDIM + 2] - X[dB * XDIM + 2];
  const float distA = rxA * rxA + ryA * ryA + rzA * rzA;
  const float distB = rxB * rxB + ryB * ryB + rzB * rzB;

  // e_inT B-fragments in registers: einB[et][ks], ks<2 -> dst feats, else src
  short8 einB[2][4];
  #pragma unroll
  for (int ks = 0; ks < 4; ++ks) {
    int nA = (ks < 2) ? dA : sA;
    int nB = (ks < 2) ? dB : sB;
    einB[0][ks] = *(const short8*)&Xb[nA * 64 + (ks & 1) * 32 + kg * 8];
    einB[1][ks] = *(const short8*)&Xb[nB * 64 + (ks & 1) * 32 + kg * 8];
  }

  const unsigned short* W1T = w1t + layer * H1T * W1T_K;
  const float* B1P = b1p + layer * H1T;
  const float* WRP = wrp + layer * H1T;
  const unsigned short* W2T = w2t + layer * MDIM * H1T;
  const float* B2 = eb2 + layer * MDIM;

  float b20 = B2[ln15], b21 = B2[16 + ln15];
  f32x4 mac[2][2];
  #pragma unroll
  for (int et = 0; et < 2; ++et) {
    mac[et][0] = (f32x4){b20, b20, b20, b20};
    mac[et][1] = (f32x4){b21, b21, b21, b21};
  }

  // ---- phases B+C in 3 chunks of 96 h-cols; all LDS wave-local, no barriers ----
  #pragma unroll 1
  for (int chunk = 0; chunk < 3; ++chunk) {
    const int jt0 = chunk * 6;
    // phase B: 6 j-tiles, one A-load feeds 2 MFMA chains (et0, et1)
    #pragma unroll 2
    for (int jl = 0; jl < 6; ++jl) {
      const int jt = jt0 + jl;
      f32x4 b4 = *(const f32x4*)&B1P[jt * 16 + kg * 4];
      f32x4 w4 = *(const f32x4*)&WRP[jt * 16 + kg * 4];
      short8 a[4];
      #pragma unroll
      for (int ks = 0; ks < 4; ++ks)
        a[ks] = *(const short8*)&W1T[(jt * 16 + ln15) * W1T_K + ks * 32 + kg * 8];
      #pragma unroll
      for (int et = 0; et < 2; ++et) {
        const float dv = et ? distB : distA;
        f32x4 acc;
        #pragma unroll
        for (int r = 0; r < 4; ++r) acc[r] = fmaf(dv, w4[r], b4[r]);
        #pragma unroll
        for (int ks = 0; ks < 4; ++ks)
          acc = __builtin_amdgcn_mfma_f32_16x16x32_bf16(a[ks], einB[et][ks], acc, 0, 0, 0);
        // C-layout: col = ln15 = edge-in-tile, rows j = jt*16 + kg*4 + r
        uint2 uu;
        uu.x = cvt_pk(fsilu(acc[0]), fsilu(acc[1]));
        uu.y = cvt_pk(fsilu(acc[2]), fsilu(acc[3]));
        *(uint2*)&hLds[(wid * 32 + et * 16 + ln15) * HSTR3 + jl * 16 + kg * 4] = uu;
      }
    }
    // phase C partial: own 32 edges, this chunk's 96 k values
    #pragma unroll
    for (int ksl = 0; ksl < 3; ++ksl) {
      const int kglob = chunk * 96 + ksl * 32;
      short8 w0 = *(const short8*)&W2T[ln15 * H1T + kglob + kg * 8];
      short8 w1 = *(const short8*)&W2T[(16 + ln15) * H1T + kglob + kg * 8];
      #pragma unroll
      for (int et = 0; et < 2; ++et) {
        short8 ah = *(const short8*)&hLds[(wid * 32 + et * 16 + ln15) * HSTR3 + ksl * 32 + kg * 8];
        mac[et][0] = __builtin_amdgcn_mfma_f32_16x16x32_bf16(ah, w0, mac[et][0], 0, 0, 0);
        mac[et][1] = __builtin_amdgcn_mfma_f32_16x16x32_bf16(ah, w1, mac[et][1], 0, 0, 0);
      }
    }
  }

  // m -> ml (wave-local): rows e = wid*32 + et*16 + kg*4 + r, cols n = ln15(+16)
  #pragma unroll
  for (int et = 0; et < 2; ++et) {
    #pragma unroll
    for (int r = 0; r < 4; ++r) {
      int eg = wid * 32 + et * 16 + kg * 4 + r;
      ml[eg * MLSTR + ln15] = f2bf(fsilu(mac[et][0][r]));
      ml[eg * MLSTR + 16 + ln15] = f2bf(fsilu(mac[et][1][r]));
    }
  }

  // ---- phase D: cw presums per et ----
  const unsigned short* CW1T = cw1t + layer * CH * MDIM;
  const float* CB1 = cb1 + layer * CH;
  const float* CW2v = cW2 + layer * CH;
  short8 amA = *(const short8*)&ml[(wid * 32 + ln15) * MLSTR + kg * 8];
  short8 amB = *(const short8*)&ml[(wid * 32 + 16 + ln15) * MLSTR + kg * 8];
  float psA[4] = {0.f, 0.f, 0.f, 0.f};
  float psB[4] = {0.f, 0.f, 0.f, 0.f};
  #pragma unroll
  for (int nt = 0; nt < 8; ++nt) {
    float cb = CB1[nt * 16 + ln15];
    float w2v = CW2v[nt * 16 + ln15];
    short8 bc = *(const short8*)&CW1T[(nt * 16 + ln15) * MDIM + kg * 8];
    f32x4 cA = {cb, cb, cb, cb};
    f32x4 cB = {cb, cb, cb, cb};
    cA = __builtin_amdgcn_mfma_f32_16x16x32_bf16(amA, bc, cA, 0, 0, 0);
    cB = __builtin_amdgcn_mfma_f32_16x16x32_bf16(amB, bc, cB, 0, 0, 0);
    #pragma unroll
    for (int r = 0; r < 4; ++r) {
      psA[r] += fsilu(cA[r]) * w2v;
      psB[r] += fsilu(cB[r]) * w2v;
    }
  }
  #pragma unroll
  for (int off = 1; off < 16; off <<= 1) {
    #pragma unroll
    for (int r = 0; r < 4; ++r) {
      psA[r] += __shfl_xor(psA[r], off, 64);
      psB[r] += __shfl_xor(psB[r], off, 64);
    }
  }
  // spread: lane l<32 gets presum of edge ew0 + l (et = l>>4, row = kg'*4+r')
  float cwvA = 0.0f, cwvB = 0.0f;
  #pragma unroll
  for (int r = 0; r < 4; ++r) {
    float tA = __shfl(psA[r], ((lane & 15) >> 2) * 16, 64);
    float tB = __shfl(psB[r], ((lane & 15) >> 2) * 16, 64);
    if ((lane & 3) == r) { cwvA = tA; cwvB = tB; }
  }

  // coalesced linear m_ij write (wave-local ml reads)
  #pragma unroll
  for (int it = 0; it < 2; ++it) {
    int idx = lane + it * 64;
    int el = idx >> 2, seg = idx & 3;
    short8 v = *(const short8*)&ml[(wid * 32 + el) * MLSTR + seg * 8];
    *(short8*)&ms[(size_t)(ew0 + el) * MDIM + seg * 8] = v;
  }
  if (lane < 32) {
    const int hi = lane >> 4;              // et of this lane's edge
    float cwv = hi ? cwvB : cwvA;
    float dv = hi ? distB : distA;
    float rx = hi ? rxB : rxA, ry = hi ? ryB : ryA, rz = hi ? rzB : rzA;
    float cw = ftanh(cwv + cb2[layer]);
    float fac = cw * cscale[layer] / fmaxf(sqrtf(dv), 1e-8f);
    *(float4*)&mh4[(size_t)(ew0 + lane) * 4] = make_float4(fac * rx, fac * ry, fac * rz, 0.0f);
  }
}

// ---- MFMA node kernel (frozen from R11) ----
__global__ __launch_bounds__(256, 3)
void node_mfma_kernel(const float* __restrict__ Xin,
                      const unsigned short* __restrict__ XbIn,
                      const unsigned short* __restrict__ ms,
                      const float* __restrict__ mh4,
                      const int* __restrict__ csr,
                      const unsigned short* __restrict__ nw1t, const float* __restrict__ nb1,
                      const unsigned short* __restrict__ nw2t, const float* __restrict__ nb2,
                      float* __restrict__ Xout, unsigned short* __restrict__ XbOut,
                      int writeXb, int layer)
{
  __shared__ unsigned short ninLds[64 * NINS];
  __shared__ unsigned short h1Lds[64 * NH1S];
  __shared__ float outLds[64 * 68];
  __shared__ float mhsLds[64][3];
  __shared__ int csrLds[65];

  const int tid = threadIdx.x;
  const int lane = tid & 63;
  const int wid = tid >> 6;
  const int ln15 = lane & 15;
  const int kg = lane >> 4;
  const int n0 = xcd_swz(blockIdx.x, gridDim.x) * 64;

  if (tid < 65) {
    int nn = n0 + tid;
    csrLds[tid] = (nn <= N_NODES) ? csr[nn] : 0;
  }
  #pragma unroll
  for (int it = 0; it < 2; ++it) {
    int idx = tid + it * 256;
    int nl = idx >> 3, c = idx & 7;
    int n = n0 + nl;
    uint4 v = make_uint4(0, 0, 0, 0);
    if (n < N_NODES) v = *(const uint4*)&XbIn[n * 64 + c * 8];
    *(uint4*)&ninLds[nl * NINS + c * 8] = v;
  }
  __syncthreads();

  {
    const int nl = tid >> 2, sub = tid & 3;
    const int n = n0 + nl;
    int off = csrLds[nl], end = csrLds[nl + 1];
    if (n >= N_NODES) { off = 0; end = 0; }
    float s0 = 0, s1 = 0, s2 = 0, s3 = 0, s4 = 0, s5 = 0, s6 = 0, s7 = 0;
    for (int r = off; r < end; ++r) {
      uint4 q = *(const uint4*)&ms[(size_t)r * MDIM + sub * 8];
      union { unsigned u; float f; } t;
      t.u = q.x << 16;         s0 += t.f;
      t.u = q.x & 0xFFFF0000u; s1 += t.f;
      t.u = q.y << 16;         s2 += t.f;
      t.u = q.y & 0xFFFF0000u; s3 += t.f;
      t.u = q.z << 16;         s4 += t.f;
      t.u = q.z & 0xFFFF0000u; s5 += t.f;
      t.u = q.w << 16;         s6 += t.f;
      t.u = q.w & 0xFFFF0000u; s7 += t.f;
    }
    uint4 mo;
    mo.x = cvt_pk(s0, s1);
    mo.y = cvt_pk(s2, s3);
    mo.z = cvt_pk(s4, s5);
    mo.w = cvt_pk(s6, s7);
    *(uint4*)&ninLds[nl * NINS + FDIM + sub * 8] = mo;

    float mx = 0, my = 0, mz = 0;
    for (int r = off + sub; r < end; r += 4) {
      float4 q = *(const float4*)&mh4[(size_t)r * 4];
      mx += q.x; my += q.y; mz += q.z;
    }
    mx += __shfl_xor(mx, 1, 64); mx += __shfl_xor(mx, 2, 64);
    my += __shfl_xor(my, 1, 64); my += __shfl_xor(my, 2, 64);
    mz += __shfl_xor(mz, 1, 64); mz += __shfl_xor(mz, 2, 64);
    if (sub == 0) {
      mhsLds[nl][0] = mx; mhsLds[nl][1] = my; mhsLds[nl][2] = mz;
    }
  }
  __syncthreads();

  const unsigned short* W1 = nw1t + layer * NH * NINS;
  const float* B1 = nb1 + layer * NH;
  for (int jt = wid; jt < 8; jt += 4) {
    f32x4 b4 = *(const f32x4*)&B1[jt * 16 + kg * 4];
    short8 a[3];
    #pragma unroll
    for (int ks = 0; ks < 3; ++ks)
      a[ks] = *(const short8*)&W1[(jt * 16 + ln15) * NINS + ks * 32 + kg * 8];
    #pragma unroll
    for (int et = 0; et < 4; ++et) {
      f32x4 acc = b4;
      #pragma unroll
      for (int ks = 0; ks < 3; ++ks) {
        short8 b = *(const short8*)&ninLds[(et * 16 + ln15) * NINS + ks * 32 + kg * 8];
        acc = __builtin_amdgcn_mfma_f32_16x16x32_bf16(a[ks], b, acc, 0, 0, 0);
      }
      uint2 uu;
      uu.x = cvt_pk(fsilu(acc[0]), fsilu(acc[1]));
      uu.y = cvt_pk(fsilu(acc[2]), fsilu(acc[3]));
      *(uint2*)&h1Lds[(et * 16 + ln15) * NH1S + jt * 16 + kg * 4] = uu;
    }
  }
  __syncthreads();

  const unsigned short* W2 = nw2t + layer * FDIM * NW2K;
  const float* B2 = nb2 + layer * FDIM;
  {
    int jt = wid;
    f32x4 b4 = *(const f32x4*)&B2[jt * 16 + kg * 4];
    short8 a[4];
    #pragma unroll
    for (int ks = 0; ks < 4; ++ks)
      a[ks] = *(const short8*)&W2[(jt * 16 + ln15) * NW2K + ks * 32 + kg * 8];
    #pragma unroll
    for (int et = 0; et < 4; ++et) {
      f32x4 acc = b4;
      #pragma unroll
      for (int ks = 0; ks < 4; ++ks) {
        short8 b = *(const short8*)&h1Lds[(et * 16 + ln15) * NH1S + ks * 32 + kg * 8];
        acc = __builtin_amdgcn_mfma_f32_16x16x32_bf16(a[ks], b, acc, 0, 0, 0);
      }
      *(f32x4*)&outLds[(et * 16 + ln15) * 68 + jt * 16 + kg * 4] = acc;
    }
  }
  __syncthreads();

  #pragma unroll
  for (int it = 0; it < 16; ++it) {
    int idx = tid + it * 256;
    int nl = idx >> 6, c = idx & 63;
    int n = n0 + nl;
    if (n < N_NODES) {
      float v = Xin[n * XDIM + PDIM + c] + outLds[nl * 68 + c];
      Xout[n * XDIM + PDIM + c] = v;
      if (writeXb) XbOut[n * 64 + c] = f2bf(v);
    }
  }
  if (tid < 64) {
    int n = n0 + tid;
    if (n < N_NODES) {
      Xout[n * XDIM + 0] = Xin[n * XDIM + 0] + mhsLds[tid][0];
      Xout[n * XDIM + 1] = Xin[n * XDIM + 1] + mhsLds[tid][1];
      Xout[n * XDIM + 2] = Xin[n * XDIM + 2] + mhsLds[tid][2];
    }
  }
}

extern "C" void kernel_launch(void* const* d_in, const int* in_sizes, int n_in,
                              void* d_out, int out_size, void* d_ws, size_t ws_size,
                              hipStream_t stream) {
  const float* x      = (const float*)d_in[0];
  const int*   ei     = (const int*)d_in[1];
  const float* eW1    = (const float*)d_in[2];
  const float* eb1    = (const float*)d_in[3];
  const float* eW2    = (const float*)d_in[4];
  const float* eb2    = (const float*)d_in[5];
  const float* cW1    = (const float*)d_in[6];
  const float* cb1    = (const float*)d_in[7];
  const float* cW2    = (const float*)d_in[8];
  const float* cb2    = (const float*)d_in[9];
  const float* nW1    = (const float*)d_in[10];
  const float* nb1    = (const float*)d_in[11];
  const float* nW2    = (const float*)d_in[12];
  const float* nb2    = (const float*)d_in[13];
  const float* cscale = (const float*)d_in[14];

  float* ws     = (float*)d_ws;
  float* X1     = ws;                                   // N*67 f32
  float* mh4    = X1 + N_NODES * XDIM;                  // E*4 f32
  int*   csr    = (int*)(mh4 + (size_t)N_EDGES * 4);    // N+4
  int*   cursor = csr + N_NODES + 4;                    // N
  int*   cnt    = cursor + N_NODES;                     // N
  int*   srcS   = cnt + N_NODES;                        // E
  int*   dstS   = srcS + N_EDGES;                       // E
  unsigned short* w1t  = (unsigned short*)(dstS + N_EDGES);
  unsigned short* w2t  = w1t + NLAYERS * H1T * W1T_K;
  unsigned short* cw1t = w2t + NLAYERS * MDIM * H1T;
  unsigned short* nw1t = cw1t + NLAYERS * CH * MDIM;
  unsigned short* nw2t = nw1t + NLAYERS * NH * NINS;
  float* b1p = (float*)(nw2t + NLAYERS * FDIM * NW2K);
  float* wrp = b1p + NLAYERS * H1T;
  unsigned short* Xb = (unsigned short*)(wrp + NLAYERS * H1T);  // N*64 bf16
  unsigned short* ms = Xb + (size_t)N_NODES * 64;               // E*32 bf16

  hipMemsetAsync(cnt, 0, N_NODES * sizeof(int), stream);
  count_kernel<<<(N_EDGES + 255) / 256, 256, 0, stream>>>(ei, cnt);
  scan_kernel<<<1, 1024, 0, stream>>>(cnt, csr, cursor);
  rank_kernel<<<(N_EDGES + 255) / 256, 256, 0, stream>>>(ei, cursor, srcS, dstS);
  {
    const int total = NLAYERS * (H1T * W1T_K + MDIM * H1T + CH * MDIM + 2 * H1T
                                 + NH * NINS + FDIM * NW2K);
    prep_weights<<<(total + 255) / 256, 256, 0, stream>>>(
        eW1, eW2, cW1, eb1, nW1, nW2, w1t, w2t, cw1t, nw1t, nw2t, b1p, wrp);
  }
  convert_x<<<(N_NODES * 8 + 255) / 256, 256, 0, stream>>>(x, Xb);

  const int nodeBlocks = (N_NODES + 63) / 64;
  for (int l = 0; l < NLAYERS; ++l) {
    const float* Xin = (l == 0) ? x : X1;
    float* Xout = (l == 0) ? X1 : (float*)d_out;
    edge_mfma_kernel<<<N_EDGES / 128, 256, 0, stream>>>(
        Xin, Xb, srcS, dstS, w1t, b1p, wrp, w2t, eb2, cw1t, cb1, cW2, cb2, cscale,
        ms, mh4, l);
    node_mfma_kernel<<<nodeBlocks, 256, 0, stream>>>(
        Xin, Xb, ms, mh4, csr, nw1t, nb1, nw2t, nb2, Xout, Xb, (l == 0) ? 1 : 0, l);
  }
}

// Round 13
// 661.506 us; speedup vs baseline: 1.8020x; 1.0468x over previous
//
#include <hip/hip_runtime.h>

#define N_NODES 50000
#define N_EDGES 800000
#define PDIM 3
#define FDIM 64
#define MDIM 32
#define NLAYERS 2
#define EINDIM 129
#define H1 258
#define CH 128
#define NH 128
#define XDIM 67
#define H1T 288
#define HSTR3 104
#define W1T_K 136
#define MLSTR 40
#define NINS 104
#define NH1S 136
#define NW2K 128

typedef __attribute__((ext_vector_type(8))) short short8;
typedef __attribute__((ext_vector_type(4))) float f32x4;

#define LOG2E 1.4426950408889634f

__device__ __forceinline__ float fsilu(float x) {
  float e = __builtin_amdgcn_exp2f(-x * LOG2E);
  return x * __builtin_amdgcn_rcpf(1.0f + e);
}

__device__ __forceinline__ float ftanh(float x) {
  float xc = fminf(fmaxf(x, -15.0f), 15.0f);
  float E = __builtin_amdgcn_exp2f(2.0f * LOG2E * xc);
  return (E - 1.0f) * __builtin_amdgcn_rcpf(E + 1.0f);
}

__device__ __forceinline__ unsigned short f2bf(float f) {
  union { float f; unsigned u; } v; v.f = f;
  unsigned r = v.u + 0x7FFF + ((v.u >> 16) & 1);  // RNE
  return (unsigned short)(r >> 16);
}

__device__ __forceinline__ unsigned cvt_pk(float lo, float hi) {
  unsigned r;
  asm("v_cvt_pk_bf16_f32 %0, %1, %2" : "=v"(r) : "v"(lo), "v"(hi));
  return r;
}

// bijective XCD-chunk swizzle (m204)
__device__ __forceinline__ int xcd_swz(int bid, int nwg) {
  const int nx = 8;
  int q = nwg / nx, r = nwg % nx;
  int xcd = bid % nx, idx = bid / nx;
  return (xcd < r) ? xcd * (q + 1) + idx : r * (q + 1) + (xcd - r) * q + idx;
}

#define COUNT_BLOCKS 3125   // 800000/256
#define PREP_TOTAL (NLAYERS * (H1T * W1T_K + MDIM * H1T + CH * MDIM + 2 * H1T \
                               + NH * NINS + FDIM * NW2K))
#define PREP_BLOCKS ((PREP_TOTAL + 255) / 256)
#define CONV_BLOCKS ((N_NODES * 8 + 255) / 256)

// fused setup: count histogram + weight prep + X bf16 conversion (independent)
__global__ void setup_kernel(const int* __restrict__ ei, int* __restrict__ cnt,
                             const float* __restrict__ eW1, const float* __restrict__ eW2,
                             const float* __restrict__ cW1, const float* __restrict__ eb1,
                             const float* __restrict__ nW1, const float* __restrict__ nW2,
                             unsigned short* __restrict__ w1t, unsigned short* __restrict__ w2t,
                             unsigned short* __restrict__ cw1t,
                             unsigned short* __restrict__ nw1t, unsigned short* __restrict__ nw2t,
                             float* __restrict__ b1p, float* __restrict__ wrp,
                             const float* __restrict__ X, unsigned short* __restrict__ Xb) {
  const int bid = blockIdx.x;
  const int tid = threadIdx.x;
  if (bid < COUNT_BLOCKS) {
    int e = bid * 256 + tid;
    if (e < N_EDGES) atomicAdd(&cnt[ei[N_EDGES + e]], 1);
    return;
  }
  if (bid < COUNT_BLOCKS + PREP_BLOCKS) {
    int idx = (bid - COUNT_BLOCKS) * 256 + tid;
    const int n1 = NLAYERS * H1T * W1T_K;
    const int n2 = NLAYERS * MDIM * H1T;
    const int n3 = NLAYERS * CH * MDIM;
    const int n4 = NLAYERS * H1T;
    const int n5 = NLAYERS * NH * NINS;
    const int n6 = NLAYERS * FDIM * NW2K;
    if (idx < n1) {
      int k = idx % W1T_K;
      int rest = idx / W1T_K;
      int j = rest % H1T;
      int l = rest / H1T;
      float v = (k < 128 && j < H1) ? eW1[(l * EINDIM + k) * H1 + j] : 0.0f;
      w1t[idx] = f2bf(v);
    } else if (idx < n1 + n2) {
      int t = idx - n1;
      int k = t % H1T;
      int rest = t / H1T;
      int n = rest % MDIM;
      int l = rest / MDIM;
      float v = (k < H1) ? eW2[(l * H1 + k) * MDIM + n] : 0.0f;
      w2t[t] = f2bf(v);
    } else if (idx < n1 + n2 + n3) {
      int t = idx - n1 - n2;
      int k = t % MDIM;
      int rest = t / MDIM;
      int n = rest % CH;
      int l = rest / CH;
      cw1t[t] = f2bf(cW1[(l * MDIM + k) * CH + n]);
    } else if (idx < n1 + n2 + n3 + n4) {
      int t = idx - n1 - n2 - n3;
      int j = t % H1T;
      int l = t / H1T;
      b1p[t] = (j < H1) ? eb1[l * H1 + j] : 0.0f;
    } else if (idx < n1 + n2 + n3 + 2 * n4) {
      int t = idx - n1 - n2 - n3 - n4;
      int j = t % H1T;
      int l = t / H1T;
      wrp[t] = (j < H1) ? eW1[((size_t)l * EINDIM + 128) * H1 + j] : 0.0f;
    } else if (idx < n1 + n2 + n3 + 2 * n4 + n5) {
      int t = idx - n1 - n2 - n3 - 2 * n4;
      int k = t % NINS;
      int rest = t / NINS;
      int j = rest % NH;
      int l = rest / NH;
      float v = (k < FDIM + MDIM) ? nW1[(l * (FDIM + MDIM) + k) * NH + j] : 0.0f;
      nw1t[t] = f2bf(v);
    } else if (idx < n1 + n2 + n3 + 2 * n4 + n5 + n6) {
      int t = idx - n1 - n2 - n3 - 2 * n4 - n5;
      int k = t % NW2K;
      int rest = t / NW2K;
      int j = rest % FDIM;
      int l = rest / FDIM;
      nw2t[t] = f2bf(nW2[(l * NH + k) * FDIM + j]);
    }
    return;
  }
  {
    int idx = (bid - COUNT_BLOCKS - PREP_BLOCKS) * 256 + tid;
    if (idx >= N_NODES * 8) return;
    int n = idx >> 3, c = idx & 7;
    const float* src = X + n * XDIM + PDIM + c * 8;
    short8 v;
    #pragma unroll
    for (int i = 0; i < 8; ++i) v[i] = (short)f2bf(src[i]);
    *(short8*)&Xb[n * 64 + c * 8] = v;
  }
}

__global__ __launch_bounds__(1024)
void scan_kernel(const int* __restrict__ cnt, int* __restrict__ csr, int* __restrict__ cursor) {
  __shared__ int partial[1024];
  const int tid = threadIdx.x;
  const int CHUNK = 49;
  int base = tid * CHUNK;
  int s = 0;
  for (int i = 0; i < CHUNK; ++i) {
    int idx = base + i;
    if (idx < N_NODES) s += cnt[idx];
  }
  partial[tid] = s;
  __syncthreads();
  for (int off = 1; off < 1024; off <<= 1) {
    int v = (tid >= off) ? partial[tid - off] : 0;
    __syncthreads();
    partial[tid] += v;
    __syncthreads();
  }
  int run = partial[tid] - s;
  for (int i = 0; i < CHUNK; ++i) {
    int idx = base + i;
    if (idx < N_NODES) {
      csr[idx] = run;
      cursor[idx] = run;
      run += cnt[idx];
    }
  }
  if (tid == 1023) csr[N_NODES] = run;
}

__global__ void rank_kernel(const int* __restrict__ ei, int* __restrict__ cursor,
                            int* __restrict__ srcS, int* __restrict__ dstS) {
  int e = blockIdx.x * 256 + threadIdx.x;
  if (e < N_EDGES) {
    int s = ei[e];
    int d = ei[N_EDGES + e];
    int p = atomicAdd(&cursor[d], 1);
    srcS[p] = s;
    dstS[p] = d;
  }
}

// ---- edge kernel (frozen from R12: 220us) ----
__global__ __launch_bounds__(256, 4)
void edge_mfma_kernel(const float* __restrict__ X,
                      const unsigned short* __restrict__ Xb,
                      const int* __restrict__ srcS, const int* __restrict__ dstS,
                      const unsigned short* __restrict__ w1t,
                      const float* __restrict__ b1p, const float* __restrict__ wrp,
                      const unsigned short* __restrict__ w2t, const float* __restrict__ eb2,
                      const unsigned short* __restrict__ cw1t, const float* __restrict__ cb1,
                      const float* __restrict__ cW2, const float* __restrict__ cb2,
                      const float* __restrict__ cscale,
                      unsigned short* __restrict__ ms, float* __restrict__ mh4,
                      int layer)
{
  __shared__ unsigned short hLds[128 * HSTR3];
  __shared__ unsigned short ml[128 * MLSTR];

  const int tid = threadIdx.x;
  const int lane = tid & 63;
  const int wid = tid >> 6;
  const int ln15 = lane & 15;
  const int kg = lane >> 4;
  const int e0 = xcd_swz(blockIdx.x, gridDim.x) * 128;
  const int ew0 = e0 + wid * 32;

  const int eA = ew0 + ln15;
  const int eB = ew0 + 16 + ln15;
  const int sA = srcS[eA], dA = dstS[eA];
  const int sB = srcS[eB], dB = dstS[eB];
  float rxA = X[sA * XDIM + 0] - X[dA * XDIM + 0];
  float ryA = X[sA * XDIM + 1] - X[dA * XDIM + 1];
  float rzA = X[sA * XDIM + 2] - X[dA * XDIM + 2];
  float rxB = X[sB * XDIM + 0] - X[dB * XDIM + 0];
  float ryB = X[sB * XDIM + 1] - X[dB * XDIM + 1];
  float rzB = X[sB * XDIM + 2] - X[dB * XDIM + 2];
  const float distA = rxA * rxA + ryA * ryA + rzA * rzA;
  const float distB = rxB * rxB + ryB * ryB + rzB * rzB;

  short8 einB[2][4];
  #pragma unroll
  for (int ks = 0; ks < 4; ++ks) {
    int nA = (ks < 2) ? dA : sA;
    int nB = (ks < 2) ? dB : sB;
    einB[0][ks] = *(const short8*)&Xb[nA * 64 + (ks & 1) * 32 + kg * 8];
    einB[1][ks] = *(const short8*)&Xb[nB * 64 + (ks & 1) * 32 + kg * 8];
  }

  const unsigned short* W1T = w1t + layer * H1T * W1T_K;
  const float* B1P = b1p + layer * H1T;
  const float* WRP = wrp + layer * H1T;
  const unsigned short* W2T = w2t + layer * MDIM * H1T;
  const float* B2 = eb2 + layer * MDIM;

  float b20 = B2[ln15], b21 = B2[16 + ln15];
  f32x4 mac[2][2];
  #pragma unroll
  for (int et = 0; et < 2; ++et) {
    mac[et][0] = (f32x4){b20, b20, b20, b20};
    mac[et][1] = (f32x4){b21, b21, b21, b21};
  }

  #pragma unroll 1
  for (int chunk = 0; chunk < 3; ++chunk) {
    const int jt0 = chunk * 6;
    #pragma unroll 2
    for (int jl = 0; jl < 6; ++jl) {
      const int jt = jt0 + jl;
      f32x4 b4 = *(const f32x4*)&B1P[jt * 16 + kg * 4];
      f32x4 w4 = *(const f32x4*)&WRP[jt * 16 + kg * 4];
      short8 a[4];
      #pragma unroll
      for (int ks = 0; ks < 4; ++ks)
        a[ks] = *(const short8*)&W1T[(jt * 16 + ln15) * W1T_K + ks * 32 + kg * 8];
      #pragma unroll
      for (int et = 0; et < 2; ++et) {
        const float dv = et ? distB : distA;
        f32x4 acc;
        #pragma unroll
        for (int r = 0; r < 4; ++r) acc[r] = fmaf(dv, w4[r], b4[r]);
        #pragma unroll
        for (int ks = 0; ks < 4; ++ks)
          acc = __builtin_amdgcn_mfma_f32_16x16x32_bf16(a[ks], einB[et][ks], acc, 0, 0, 0);
        uint2 uu;
        uu.x = cvt_pk(fsilu(acc[0]), fsilu(acc[1]));
        uu.y = cvt_pk(fsilu(acc[2]), fsilu(acc[3]));
        *(uint2*)&hLds[(wid * 32 + et * 16 + ln15) * HSTR3 + jl * 16 + kg * 4] = uu;
      }
    }
    #pragma unroll
    for (int ksl = 0; ksl < 3; ++ksl) {
      const int kglob = chunk * 96 + ksl * 32;
      short8 w0 = *(const short8*)&W2T[ln15 * H1T + kglob + kg * 8];
      short8 w1 = *(const short8*)&W2T[(16 + ln15) * H1T + kglob + kg * 8];
      #pragma unroll
      for (int et = 0; et < 2; ++et) {
        short8 ah = *(const short8*)&hLds[(wid * 32 + et * 16 + ln15) * HSTR3 + ksl * 32 + kg * 8];
        mac[et][0] = __builtin_amdgcn_mfma_f32_16x16x32_bf16(ah, w0, mac[et][0], 0, 0, 0);
        mac[et][1] = __builtin_amdgcn_mfma_f32_16x16x32_bf16(ah, w1, mac[et][1], 0, 0, 0);
      }
    }
  }

  #pragma unroll
  for (int et = 0; et < 2; ++et) {
    #pragma unroll
    for (int r = 0; r < 4; ++r) {
      int eg = wid * 32 + et * 16 + kg * 4 + r;
      ml[eg * MLSTR + ln15] = f2bf(fsilu(mac[et][0][r]));
      ml[eg * MLSTR + 16 + ln15] = f2bf(fsilu(mac[et][1][r]));
    }
  }

  const unsigned short* CW1T = cw1t + layer * CH * MDIM;
  const float* CB1 = cb1 + layer * CH;
  const float* CW2v = cW2 + layer * CH;
  short8 amA = *(const short8*)&ml[(wid * 32 + ln15) * MLSTR + kg * 8];
  short8 amB = *(const short8*)&ml[(wid * 32 + 16 + ln15) * MLSTR + kg * 8];
  float psA[4] = {0.f, 0.f, 0.f, 0.f};
  float psB[4] = {0.f, 0.f, 0.f, 0.f};
  #pragma unroll
  for (int nt = 0; nt < 8; ++nt) {
    float cb = CB1[nt * 16 + ln15];
    float w2v = CW2v[nt * 16 + ln15];
    short8 bc = *(const short8*)&CW1T[(nt * 16 + ln15) * MDIM + kg * 8];
    f32x4 cA = {cb, cb, cb, cb};
    f32x4 cB = {cb, cb, cb, cb};
    cA = __builtin_amdgcn_mfma_f32_16x16x32_bf16(amA, bc, cA, 0, 0, 0);
    cB = __builtin_amdgcn_mfma_f32_16x16x32_bf16(amB, bc, cB, 0, 0, 0);
    #pragma unroll
    for (int r = 0; r < 4; ++r) {
      psA[r] += fsilu(cA[r]) * w2v;
      psB[r] += fsilu(cB[r]) * w2v;
    }
  }
  #pragma unroll
  for (int off = 1; off < 16; off <<= 1) {
    #pragma unroll
    for (int r = 0; r < 4; ++r) {
      psA[r] += __shfl_xor(psA[r], off, 64);
      psB[r] += __shfl_xor(psB[r], off, 64);
    }
  }
  float cwvA = 0.0f, cwvB = 0.0f;
  #pragma unroll
  for (int r = 0; r < 4; ++r) {
    float tA = __shfl(psA[r], ((lane & 15) >> 2) * 16, 64);
    float tB = __shfl(psB[r], ((lane & 15) >> 2) * 16, 64);
    if ((lane & 3) == r) { cwvA = tA; cwvB = tB; }
  }

  #pragma unroll
  for (int it = 0; it < 2; ++it) {
    int idx = lane + it * 64;
    int el = idx >> 2, seg = idx & 3;
    short8 v = *(const short8*)&ml[(wid * 32 + el) * MLSTR + seg * 8];
    *(short8*)&ms[(size_t)(ew0 + el) * MDIM + seg * 8] = v;
  }
  if (lane < 32) {
    const int hi = lane >> 4;
    float cwv = hi ? cwvB : cwvA;
    float dv = hi ? distB : distA;
    float rx = hi ? rxB : rxA, ry = hi ? ryB : ryA, rz = hi ? rzB : rzA;
    float cw = ftanh(cwv + cb2[layer]);
    float fac = cw * cscale[layer] / fmaxf(sqrtf(dv), 1e-8f);
    *(float4*)&mh4[(size_t)(ew0 + lane) * 4] = make_float4(fac * rx, fac * ry, fac * rz, 0.0f);
  }
}

// ---- MFMA node kernel v2: 31KB LDS (outLds unioned onto h1Lds), direct coors ----
__global__ __launch_bounds__(256, 5)
void node_mfma_kernel(const float* __restrict__ Xin,
                      const unsigned short* __restrict__ XbIn,
                      const unsigned short* __restrict__ ms,
                      const float* __restrict__ mh4,
                      const int* __restrict__ csr,
                      const unsigned short* __restrict__ nw1t, const float* __restrict__ nb1,
                      const unsigned short* __restrict__ nw2t, const float* __restrict__ nb2,
                      float* __restrict__ Xout, unsigned short* __restrict__ XbOut,
                      int writeXb, int layer)
{
  __shared__ unsigned short ninLds[64 * NINS];  // 13312 B
  __shared__ unsigned short h1Lds[64 * NH1S];   // 17408 B, reused as f32 out[64][68]
  __shared__ int csrLds[65];
  float* outLds = (float*)h1Lds;

  const int tid = threadIdx.x;
  const int lane = tid & 63;
  const int wid = tid >> 6;
  const int ln15 = lane & 15;
  const int kg = lane >> 4;
  const int n0 = xcd_swz(blockIdx.x, gridDim.x) * 64;

  if (tid < 65) {
    int nn = n0 + tid;
    csrLds[tid] = (nn <= N_NODES) ? csr[nn] : 0;
  }
  #pragma unroll
  for (int it = 0; it < 2; ++it) {
    int idx = tid + it * 256;
    int nl = idx >> 3, c = idx & 7;
    int n = n0 + nl;
    uint4 v = make_uint4(0, 0, 0, 0);
    if (n < N_NODES) v = *(const uint4*)&XbIn[n * 64 + c * 8];
    *(uint4*)&ninLds[nl * NINS + c * 8] = v;
  }
  __syncthreads();

  // gather m_i + mhat; 4 threads/node; coors written directly
  {
    const int nl = tid >> 2, sub = tid & 3;
    const int n = n0 + nl;
    int off = csrLds[nl], end = csrLds[nl + 1];
    if (n >= N_NODES) { off = 0; end = 0; }
    float s0 = 0, s1 = 0, s2 = 0, s3 = 0, s4 = 0, s5 = 0, s6 = 0, s7 = 0;
    for (int r = off; r < end; ++r) {
      uint4 q = *(const uint4*)&ms[(size_t)r * MDIM + sub * 8];
      union { unsigned u; float f; } t;
      t.u = q.x << 16;         s0 += t.f;
      t.u = q.x & 0xFFFF0000u; s1 += t.f;
      t.u = q.y << 16;         s2 += t.f;
      t.u = q.y & 0xFFFF0000u; s3 += t.f;
      t.u = q.z << 16;         s4 += t.f;
      t.u = q.z & 0xFFFF0000u; s5 += t.f;
      t.u = q.w << 16;         s6 += t.f;
      t.u = q.w & 0xFFFF0000u; s7 += t.f;
    }
    uint4 mo;
    mo.x = cvt_pk(s0, s1);
    mo.y = cvt_pk(s2, s3);
    mo.z = cvt_pk(s4, s5);
    mo.w = cvt_pk(s6, s7);
    *(uint4*)&ninLds[nl * NINS + FDIM + sub * 8] = mo;

    float mx = 0, my = 0, mz = 0;
    for (int r = off + sub; r < end; r += 4) {
      float4 q = *(const float4*)&mh4[(size_t)r * 4];
      mx += q.x; my += q.y; mz += q.z;
    }
    mx += __shfl_xor(mx, 1, 64); mx += __shfl_xor(mx, 2, 64);
    my += __shfl_xor(my, 1, 64); my += __shfl_xor(my, 2, 64);
    mz += __shfl_xor(mz, 1, 64); mz += __shfl_xor(mz, 2, 64);
    if (sub == 0 && n < N_NODES) {
      Xout[n * XDIM + 0] = Xin[n * XDIM + 0] + mx;
      Xout[n * XDIM + 1] = Xin[n * XDIM + 1] + my;
      Xout[n * XDIM + 2] = Xin[n * XDIM + 2] + mz;
    }
  }
  __syncthreads();

  // M1: h1T = silu(nW1T . n_inT + nb1)
  const unsigned short* W1 = nw1t + layer * NH * NINS;
  const float* B1 = nb1 + layer * NH;
  for (int jt = wid; jt < 8; jt += 4) {
    f32x4 b4 = *(const f32x4*)&B1[jt * 16 + kg * 4];
    short8 a[3];
    #pragma unroll
    for (int ks = 0; ks < 3; ++ks)
      a[ks] = *(const short8*)&W1[(jt * 16 + ln15) * NINS + ks * 32 + kg * 8];
    #pragma unroll
    for (int et = 0; et < 4; ++et) {
      f32x4 acc = b4;
      #pragma unroll
      for (int ks = 0; ks < 3; ++ks) {
        short8 b = *(const short8*)&ninLds[(et * 16 + ln15) * NINS + ks * 32 + kg * 8];
        acc = __builtin_amdgcn_mfma_f32_16x16x32_bf16(a[ks], b, acc, 0, 0, 0);
      }
      uint2 uu;
      uu.x = cvt_pk(fsilu(acc[0]), fsilu(acc[1]));
      uu.y = cvt_pk(fsilu(acc[2]), fsilu(acc[3]));
      *(uint2*)&h1Lds[(et * 16 + ln15) * NH1S + jt * 16 + kg * 4] = uu;
    }
  }
  __syncthreads();

  // M2: outT = nW2T . h1T + nb2 (keep in regs, then overwrite h1Lds as f32 out)
  const unsigned short* W2 = nw2t + layer * FDIM * NW2K;
  const float* B2 = nb2 + layer * FDIM;
  f32x4 oacc[4];
  {
    int jt = wid;
    f32x4 b4 = *(const f32x4*)&B2[jt * 16 + kg * 4];
    short8 a[4];
    #pragma unroll
    for (int ks = 0; ks < 4; ++ks)
      a[ks] = *(const short8*)&W2[(jt * 16 + ln15) * NW2K + ks * 32 + kg * 8];
    #pragma unroll
    for (int et = 0; et < 4; ++et) {
      f32x4 acc = b4;
      #pragma unroll
      for (int ks = 0; ks < 4; ++ks) {
        short8 b = *(const short8*)&h1Lds[(et * 16 + ln15) * NH1S + ks * 32 + kg * 8];
        acc = __builtin_amdgcn_mfma_f32_16x16x32_bf16(a[ks], b, acc, 0, 0, 0);
      }
      oacc[et] = acc;
    }
  }
  __syncthreads();   // all M2 reads of h1Lds done
  {
    int jt = wid;
    #pragma unroll
    for (int et = 0; et < 4; ++et)
      *(f32x4*)&outLds[(et * 16 + ln15) * 68 + jt * 16 + kg * 4] = oacc[et];
  }
  __syncthreads();

  // coalesced epilogue: feats residual + optional Xb
  #pragma unroll
  for (int it = 0; it < 16; ++it) {
    int idx = tid + it * 256;
    int nl = idx >> 6, c = idx & 63;
    int n = n0 + nl;
    if (n < N_NODES) {
      float v = Xin[n * XDIM + PDIM + c] + outLds[nl * 68 + c];
      Xout[n * XDIM + PDIM + c] = v;
      if (writeXb) XbOut[n * 64 + c] = f2bf(v);
    }
  }
}

extern "C" void kernel_launch(void* const* d_in, const int* in_sizes, int n_in,
                              void* d_out, int out_size, void* d_ws, size_t ws_size,
                              hipStream_t stream) {
  const float* x      = (const float*)d_in[0];
  const int*   ei     = (const int*)d_in[1];
  const float* eW1    = (const float*)d_in[2];
  const float* eb1    = (const float*)d_in[3];
  const float* eW2    = (const float*)d_in[4];
  const float* eb2    = (const float*)d_in[5];
  const float* cW1    = (const float*)d_in[6];
  const float* cb1    = (const float*)d_in[7];
  const float* cW2    = (const float*)d_in[8];
  const float* cb2    = (const float*)d_in[9];
  const float* nW1    = (const float*)d_in[10];
  const float* nb1    = (const float*)d_in[11];
  const float* nW2    = (const float*)d_in[12];
  const float* nb2    = (const float*)d_in[13];
  const float* cscale = (const float*)d_in[14];

  float* ws     = (float*)d_ws;
  float* X1     = ws;                                   // N*67 f32
  float* mh4    = X1 + N_NODES * XDIM;                  // E*4 f32
  int*   csr    = (int*)(mh4 + (size_t)N_EDGES * 4);    // N+4
  int*   cursor = csr + N_NODES + 4;                    // N
  int*   cnt    = cursor + N_NODES;                     // N
  int*   srcS   = cnt + N_NODES;                        // E
  int*   dstS   = srcS + N_EDGES;                       // E
  unsigned short* w1t  = (unsigned short*)(dstS + N_EDGES);
  unsigned short* w2t  = w1t + NLAYERS * H1T * W1T_K;
  unsigned short* cw1t = w2t + NLAYERS * MDIM * H1T;
  unsigned short* nw1t = cw1t + NLAYERS * CH * MDIM;
  unsigned short* nw2t = nw1t + NLAYERS * NH * NINS;
  float* b1p = (float*)(nw2t + NLAYERS * FDIM * NW2K);
  float* wrp = b1p + NLAYERS * H1T;
  unsigned short* Xb = (unsigned short*)(wrp + NLAYERS * H1T);  // N*64 bf16
  unsigned short* ms = Xb + (size_t)N_NODES * 64;               // E*32 bf16

  hipMemsetAsync(cnt, 0, N_NODES * sizeof(int), stream);
  setup_kernel<<<COUNT_BLOCKS + PREP_BLOCKS + CONV_BLOCKS, 256, 0, stream>>>(
      ei, cnt, eW1, eW2, cW1, eb1, nW1, nW2,
      w1t, w2t, cw1t, nw1t, nw2t, b1p, wrp, x, Xb);
  scan_kernel<<<1, 1024, 0, stream>>>(cnt, csr, cursor);
  rank_kernel<<<(N_EDGES + 255) / 256, 256, 0, stream>>>(ei, cursor, srcS, dstS);

  const int nodeBlocks = (N_NODES + 63) / 64;
  for (int l = 0; l < NLAYERS; ++l) {
    const float* Xin = (l == 0) ? x : X1;
    float* Xout = (l == 0) ? X1 : (float*)d_out;
    edge_mfma_kernel<<<N_EDGES / 128, 256, 0, stream>>>(
        Xin, Xb, srcS, dstS, w1t, b1p, wrp, w2t, eb2, cw1t, cb1, cW2, cb2, cscale,
        ms, mh4, l);
    node_mfma_kernel<<<nodeBlocks, 256, 0, stream>>>(
        Xin, Xb, ms, mh4, csr, nw1t, nb1, nw2t, nb2, Xout, Xb, (l == 0) ? 1 : 0, l);
  }
}